// Round 17
// baseline (809.963 us; speedup 1.0000x reference)
//
#include <hip/hip_runtime.h>

// ComTransformer on MI355X — round 17: lgkm-only barriers in flash (T4/HK pattern).
//  - the compiler's __syncthreads emits s_waitcnt vmcnt(0) before s_barrier,
//    draining the V/K register prefetches every tile (the 19K-cycle/tile stall).
//    Replaced in-loop barriers with: asm lgkmcnt(0) + raw s_barrier + memory fence.
//    LDS ordering preserved; global loads now span barriers (drain at use).
// Prior: software-pipelined flash (V reg-prefetch, K dbuf), XCD-local flash grid,
// fully batched decoder, rank-1 imag collapse, pipelined BK=64 bf16 NT GEMM.

namespace {

constexpr int kNI = 3;
constexpr int kB  = 8;
constexpr int kD  = 512;
constexpr int kKD = 128;
constexpr int kHW = 484;
constexpr int kL  = kNI * kHW;  // 1452
constexpr int kLp = 1456;
constexpr int kHWp = 488;
constexpr float kTemp = 30.0f;
constexpr float kCnt  = 247808.0f;
constexpr float kScaleN = 0.011048543456039806f;
constexpr int kR = kHW * kB;   // 3872 rows per image
constexpr int kR6 = 6 * kR;    // 23232

#define CDIV(a, b) (((a) + (b) - 1) / (b))

typedef float f32x4 __attribute__((ext_vector_type(4)));
typedef unsigned int u32x4 __attribute__((ext_vector_type(4)));
typedef unsigned short u16b;

__device__ __forceinline__ float wsum(float v) {
#pragma unroll
  for (int o = 32; o; o >>= 1) v += __shfl_down(v, o);
  return v;
}
__device__ __forceinline__ float wmax(float v) {
#pragma unroll
  for (int o = 32; o; o >>= 1) v = fmaxf(v, __shfl_down(v, o));
  return v;
}

__device__ __forceinline__ unsigned pk2bf(float lo, float hi) {
  union { float f; unsigned u; } a, b;
  a.f = lo; b.f = hi;
  unsigned ra = (a.u + 0x7FFFu + ((a.u >> 16) & 1u)) >> 16;
  unsigned rb = (b.u + 0x7FFFu + ((b.u >> 16) & 1u)) >> 16;
  return (ra & 0xFFFFu) | (rb << 16);
}
__device__ __forceinline__ u16b f2bf(float x) {
  union { float f; unsigned u; } a;
  a.f = x;
  return (u16b)((a.u + 0x7FFFu + ((a.u >> 16) & 1u)) >> 16);
}
__device__ __forceinline__ float bf2f(u16b x) {
  union { unsigned u; float f; } a;
  a.u = (unsigned)x << 16;
  return a.f;
}

__device__ __forceinline__ void mfma_bf16(f32x4& d, const u32x4& a, const u32x4& b) {
  asm("v_mfma_f32_16x16x32_bf16 %0, %1, %2, %0" : "+v"(d) : "v"(a), "v"(b));
}

// LDS-only barrier: orders LDS ops across the block WITHOUT draining vmcnt
// (global register prefetches stay in flight across it).
__device__ __forceinline__ void ldsbar() {
  asm volatile("s_waitcnt lgkmcnt(0)" ::: "memory");
  __builtin_amdgcn_s_barrier();
  asm volatile("" ::: "memory");
}

// ---------------- layout transform: [n,b,d,hw] -> seq [(n*hw),b,d] fp32 -----------
__global__ void k_toseq(const float* __restrict__ in, float* __restrict__ out) {
  __shared__ float tile[32][33];
  int nb = blockIdx.z;
  int n = nb / kB, b = nb % kB;
  int p0 = blockIdx.x * 32, d0 = blockIdx.y * 32;
  int tx = threadIdx.x, ty = threadIdx.y;
#pragma unroll
  for (int j = 0; j < 4; ++j) {
    int d = d0 + ty + j * 8, p = p0 + tx;
    if (d < kD && p < kHW) tile[ty + j * 8][tx] = in[(long)nb * kD * kHW + (long)d * kHW + p];
  }
  __syncthreads();
#pragma unroll
  for (int j = 0; j < 4; ++j) {
    int p = p0 + ty + j * 8, d = d0 + tx;
    if (p < kHW && d < kD)
      out[((long)(n * kHW + p) * kB + b) * kD + d] = tile[tx][ty + j * 8];
  }
}

__global__ void k_cvt2d(const float* __restrict__ in, u16b* __restrict__ out, int C, int Cp) {
  long r = blockIdx.x;
  for (int c = threadIdx.x; c < C; c += 256)
    out[r * Cp + c] = f2bf(in[r * (long)C + c]);
}

__global__ void k_tcvt(const float* __restrict__ in, u16b* __restrict__ out, int R, int C) {
  __shared__ float tile[32][33];
  int c0 = blockIdx.x * 32, r0 = blockIdx.y * 32;
  int tx = threadIdx.x, ty = threadIdx.y;
#pragma unroll
  for (int j = 0; j < 4; ++j) {
    int r = r0 + ty + j * 8, c = c0 + tx;
    if (r < R && c < C) tile[ty + j * 8][tx] = in[(long)r * C + c];
  }
  __syncthreads();
#pragma unroll
  for (int j = 0; j < 4; ++j) {
    int c = c0 + ty + j * 8, r = r0 + tx;
    if (r < R && c < C) out[(long)c * R + r] = f2bf(tile[tx][ty + j * 8]);
  }
}

// VrT[b][d][l] = bf16( mr[(l,b),d] * lab[l,b] ), stride kLp
__global__ void k_vrt(const float* __restrict__ mr, const float* __restrict__ lab,
                      u16b* __restrict__ vt) {
  __shared__ float tile[32][33];
  int l0 = blockIdx.x * 32, d0 = blockIdx.y * 32, b = blockIdx.z;
  int tx = threadIdx.x, ty = threadIdx.y;
#pragma unroll
  for (int j = 0; j < 4; ++j) {
    int l = l0 + ty + j * 8;
    if (l < kL)
      tile[ty + j * 8][tx] = mr[((long)l * kB + b) * kD + d0 + tx] * lab[(long)l * kB + b];
  }
  __syncthreads();
#pragma unroll
  for (int j = 0; j < 4; ++j) {
    int d = d0 + ty + j * 8, l = l0 + tx;
    if (l < kL) vt[((long)b * kD + d) * kLp + l] = f2bf(tile[tx][ty + j * 8]);
  }
}

__global__ void k_lab(const float* __restrict__ tl, float* __restrict__ lab) {
  long i = (long)blockIdx.x * 256 + threadIdx.x;
  const long tot = (long)kNI * kB * kHW;
  if (i >= tot) return;
  int p = (int)(i % kHW);
  long t = i / kHW;
  int b = (int)(t % kB);
  int n = (int)(t / kB);
  lab[(long)(n * kHW + p) * kB + b] = tl[i];
}

__global__ void k_l2n_vec(const float* __restrict__ src, float* __restrict__ u, int C) {
  __shared__ float red[2];
  int tid = threadIdx.x;  // 128
  float s = 0.f;
  for (int c = tid; c < C; c += 128) { float x = src[c]; s += x * x; }
  s = wsum(s);
  if ((tid & 63) == 0) red[tid >> 6] = s;
  __syncthreads();
  float inv = 1.f / fmaxf(sqrtf(red[0] + red[1]), 1e-12f);
  for (int c = tid; c < C; c += 128) u[c] = src[c] * inv;
}

// ---------------- pipelined NT bf16 MFMA GEMM (XCD swizzle, 2-stride batch) -------
template <int BM, int BN, bool AF32, bool ACC>
__global__ __launch_bounds__(256) void k_gemm(const void* Ap, const u16b* __restrict__ B,
                                              float* __restrict__ C, int M, int N, int K,
                                              int lda, int ldb, int ldc,
                                              long sA1, long sA2, long sB1, long sB2,
                                              long sC1, long sC2,
                                              const float* __restrict__ addv) {
  const int gx = gridDim.x, gy = gridDim.y;
  const int nwg = gx * gy * gridDim.z;
  const int orig = (blockIdx.z * gy + blockIdx.y) * gx + blockIdx.x;
  const int q = nwg >> 3, rr = nwg & 7, xcd = orig & 7, idx = orig >> 3;
  const int swz = (xcd < rr ? xcd * (q + 1) : rr * (q + 1) + (xcd - rr) * q) + idx;
  const int bx = swz % gx;
  const int tmp = swz / gx;
  const int by = tmp % gy, bz = tmp / gy;
  const int za = bz >> 3, zb = bz & 7;

  const char* Ab = (const char*)Ap + (za * sA1 + zb * sA2) * (AF32 ? 4 : 2);
  const u16b* Bb = B + za * sB1 + zb * sB2;
  C += za * sC1 + zb * sC2;
  constexpr int FM = BM / 32, FN = BN / 32;
  constexpr int NSA = BM * 8 / 256;
  constexpr int NSB = BN * 8 / 256;
  const int m0 = by * BM, n0 = bx * BN;
  const int tid = threadIdx.x;
  const int wid = tid >> 6, lane = tid & 63;
  const int wr = wid >> 1, wc = wid & 1;
  const int fr = lane & 15, fk = lane >> 4;

  __shared__ unsigned AsU[BM * 36];
  __shared__ unsigned BsU[BN * 36];
  f32x4 acc[FM][FN] = {};

  u32x4 pa[NSA];
  float4 paf[AF32 ? 2 * NSA : 1];
  u32x4 pb[NSB];

  auto loadA = [&](int k0) {
#pragma unroll
    for (int i = 0; i < NSA; ++i) {
      int si = tid + i * 256;
      int row = si >> 3, c = si & 7;
      int gr = m0 + row, gk = k0 + c * 8;
      if constexpr (AF32) {
        const float* A = (const float*)Ab;
        if (gr < M && gk + 8 <= K) {
          const float* ap = A + (long)gr * lda + gk;
          paf[2 * i] = *(const float4*)ap;
          paf[2 * i + 1] = *(const float4*)(ap + 4);
        } else {
          float v[8];
#pragma unroll
          for (int j = 0; j < 8; ++j)
            v[j] = (gr < M && gk + j < K) ? A[(long)gr * lda + gk + j] : 0.f;
          paf[2 * i] = make_float4(v[0], v[1], v[2], v[3]);
          paf[2 * i + 1] = make_float4(v[4], v[5], v[6], v[7]);
        }
      } else {
        const u16b* A = (const u16b*)Ab;
        if (gr < M && gk + 8 <= K) {
          pa[i] = *(const u32x4*)(A + (long)gr * lda + gk);
        } else {
          unsigned v[8];
#pragma unroll
          for (int j = 0; j < 8; ++j)
            v[j] = (gr < M && gk + j < K) ? A[(long)gr * lda + gk + j] : 0u;
          pa[i].x = v[0] | (v[1] << 16); pa[i].y = v[2] | (v[3] << 16);
          pa[i].z = v[4] | (v[5] << 16); pa[i].w = v[6] | (v[7] << 16);
        }
      }
    }
  };
  auto loadB = [&](int k0) {
#pragma unroll
    for (int i = 0; i < NSB; ++i) {
      int si = tid + i * 256;
      int row = si >> 3, c = si & 7;
      int gr = n0 + row, gk = k0 + c * 8;
      if (gr < N && gk + 8 <= K) {
        pb[i] = *(const u32x4*)(Bb + (long)gr * ldb + gk);
      } else {
        unsigned v[8];
#pragma unroll
        for (int j = 0; j < 8; ++j)
          v[j] = (gr < N && gk + j < K) ? Bb[(long)gr * ldb + gk + j] : 0u;
        pb[i].x = v[0] | (v[1] << 16); pb[i].y = v[2] | (v[3] << 16);
        pb[i].z = v[4] | (v[5] << 16); pb[i].w = v[6] | (v[7] << 16);
      }
    }
  };
  auto storeAB = [&]() {
#pragma unroll
    for (int i = 0; i < NSA; ++i) {
      int si = tid + i * 256;
      int row = si >> 3, c = si & 7;
      u32x4 w;
      if constexpr (AF32) {
        float4 u0 = paf[2 * i], u1 = paf[2 * i + 1];
        w.x = pk2bf(u0.x, u0.y); w.y = pk2bf(u0.z, u0.w);
        w.z = pk2bf(u1.x, u1.y); w.w = pk2bf(u1.z, u1.w);
      } else {
        w = pa[i];
      }
      *(u32x4*)&AsU[row * 36 + c * 4] = w;
    }
#pragma unroll
    for (int i = 0; i < NSB; ++i) {
      int si = tid + i * 256;
      int row = si >> 3, c = si & 7;
      *(u32x4*)&BsU[row * 36 + c * 4] = pb[i];
    }
  };

  loadA(0);
  loadB(0);
  storeAB();
  __syncthreads();
  const int nk = CDIV(K, 64);
  for (int t = 0; t < nk; ++t) {
    const bool more = (t + 1 < nk);
    if (more) { loadA((t + 1) * 64); loadB((t + 1) * 64); }
#pragma unroll
    for (int kk = 0; kk < 2; ++kk) {
      u32x4 af[FM], bf[FN];
#pragma unroll
      for (int mi = 0; mi < FM; ++mi)
        af[mi] = *(const u32x4*)&AsU[(wr * (BM / 2) + mi * 16 + fr) * 36 + kk * 16 + fk * 4];
#pragma unroll
      for (int ni = 0; ni < FN; ++ni)
        bf[ni] = *(const u32x4*)&BsU[(wc * (BN / 2) + ni * 16 + fr) * 36 + kk * 16 + fk * 4];
#pragma unroll
      for (int mi = 0; mi < FM; ++mi)
#pragma unroll
        for (int ni = 0; ni < FN; ++ni) mfma_bf16(acc[mi][ni], af[mi], bf[ni]);
    }
    if (more) {
      __syncthreads();
      storeAB();
      __syncthreads();
    }
  }
  asm volatile("s_nop 7\n\ts_nop 7" ::: );
#pragma unroll
  for (int mi = 0; mi < FM; ++mi) {
#pragma unroll
    for (int r = 0; r < 4; ++r) {
      int gm = m0 + wr * (BM / 2) + mi * 16 + fk * 4 + r;
      if (gm >= M) continue;
      float av = addv ? addv[(long)za * (kD * 8) + (long)gm * 8 + zb] : 0.f;
#pragma unroll
      for (int ni = 0; ni < FN; ++ni) {
        int gn = n0 + wc * (BN / 2) + ni * 16 + fr;
        if (gn >= N) continue;
        long idx2 = (long)gm * ldc + gn;
        float v = acc[mi][ni][r] + av;
        C[idx2] = ACC ? (C[idx2] + v) : v;
      }
    }
  }
}

// ---------------- flash attention: O = softmax(30 Q K^T) V, optional lab-dot ------
// 1-D grid, b = blockIdx.x & 7 (XCD-local K/V). V reg-prefetch, K dbuf.
// In-loop barriers are lgkm-only: global prefetches stay in flight across them.
template <bool LAB, bool KIMG, bool VZ>
__global__ __launch_bounds__(256) void k_flash(const u16b* __restrict__ Q,
                                               const u16b* __restrict__ K,
                                               const u16b* __restrict__ V,
                                               const float* __restrict__ labv,
                                               u16b* __restrict__ O,
                                               float* __restrict__ mkout,
                                               int S, int ldv) {
  int orig = blockIdx.x;
  int b = orig & 7;
  int t = orig >> 3;
  int qt0 = (t & 15) * 32;
  int img = t >> 4;
  int z = img * 8 + b;
  int tid = threadIdx.x, wid = tid >> 6, lane = tid & 63;
  int fr = lane & 15, fk = lane >> 4;

  __shared__ float Ssm[32 * 68];
  __shared__ unsigned Plds[32 * 36];
  __shared__ float mrun[32], lrun[32], scal[32], mka[32];

  const long qbase = ((long)img * kR + b) * kKD;
  const long kbase = KIMG ? ((long)img * kR + b) * kKD : (long)b * kKD;
  const long vbase = (long)(VZ ? z : b) * kD * ldv;

  u32x4 afq[2][4];
#pragma unroll
  for (int mi = 0; mi < 2; ++mi) {
    int qq = qt0 + mi * 16 + fr;
    if (qq >= kHW) qq = kHW - 1;
#pragma unroll
    for (int kk = 0; kk < 4; ++kk)
      afq[mi][kk] = *(const u32x4*)(Q + qbase + (long)qq * (kB * kKD) + kk * 32 + fk * 8);
  }

  f32x4 oacc[2][8] = {};
  if (tid < 32) { mrun[tid] = -3.0e38f; lrun[tid] = 0.f; mka[tid] = 0.f; }
  __syncthreads();

  int r8 = lane >> 3, i8 = lane & 7;
  int srow = wid * 8 + r8;

  // K double-buffer: load tile 0
  u32x4 kcur[4], knxt[4];
  {
    int krow = wid * 16 + fr;
    int kc = krow < S ? krow : S - 1;
    const u16b* kp = K + kbase + (long)kc * (kB * kKD);
#pragma unroll
    for (int kk = 0; kk < 4; ++kk) kcur[kk] = *(const u32x4*)(kp + kk * 32 + fk * 8);
  }

  for (int kt = 0; kt < S; kt += 64) {
    // QK^T strip (uses kcur)
    f32x4 sacc[2] = {};
#pragma unroll
    for (int kk = 0; kk < 4; ++kk) {
      mfma_bf16(sacc[0], afq[0][kk], kcur[kk]);
      mfma_bf16(sacc[1], afq[1][kk], kcur[kk]);
    }
    // prefetch THIS tile's V into registers (consumed after 2 barriers)
    u32x4 vreg[2][8];
#pragma unroll
    for (int kk = 0; kk < 2; ++kk) {
      int kidx = kt + kk * 32 + fk * 8;
      if (kidx > ldv - 8) kidx = ldv - 8;
#pragma unroll
      for (int n = 0; n < 8; ++n) {
        int d = wid * 128 + n * 16 + fr;
        vreg[kk][n] = *(const u32x4*)(V + vbase + (long)d * ldv + kidx);
      }
    }
    // prefetch NEXT tile's K
    const bool more = (kt + 64 < S);
    if (more) {
      int krow2 = kt + 64 + wid * 16 + fr;
      int kc2 = krow2 < S ? krow2 : S - 1;
      const u16b* kp2 = K + kbase + (long)kc2 * (kB * kKD);
#pragma unroll
      for (int kk = 0; kk < 4; ++kk) knxt[kk] = *(const u32x4*)(kp2 + kk * 32 + fk * 8);
    }
    asm volatile("s_nop 7\n\ts_nop 7" ::: );  // MFMA -> VALU hazard
    {
      int krow = kt + wid * 16 + fr;
      if (krow >= S) {
#pragma unroll
        for (int mi = 0; mi < 2; ++mi)
#pragma unroll
          for (int r = 0; r < 4; ++r) sacc[mi][r] = -1.0e30f;
      }
#pragma unroll
      for (int mi = 0; mi < 2; ++mi)
#pragma unroll
        for (int r = 0; r < 4; ++r)
          Ssm[(mi * 16 + fk * 4 + r) * 68 + wid * 16 + fr] = sacc[mi][r];
    }
    ldsbar();  // B1: Ssm RAW (lgkm-only; V/K loads stay in flight)
    // online softmax
    {
      float v[8];
      float mx = -3.0e38f;
#pragma unroll
      for (int j = 0; j < 8; ++j) {
        v[j] = Ssm[srow * 68 + i8 * 8 + j] * kTemp;
        mx = fmaxf(mx, v[j]);
      }
#pragma unroll
      for (int o = 1; o < 8; o <<= 1) mx = fmaxf(mx, __shfl_xor(mx, o));
      float mold = mrun[srow];
      float mnew = fmaxf(mold, mx);
      float p[8], ts = 0.f, lacc = 0.f;
#pragma unroll
      for (int j = 0; j < 8; ++j) {
        p[j] = __expf(v[j] - mnew);
        ts += p[j];
        if (LAB) {
          int kidx = kt + i8 * 8 + j;
          lacc += p[j] * labv[(long)(kidx < S ? kidx : S - 1) * kB + b];
        }
      }
#pragma unroll
      for (int o = 1; o < 8; o <<= 1) ts += __shfl_xor(ts, o);
      if (LAB) {
#pragma unroll
        for (int o = 1; o < 8; o <<= 1) lacc += __shfl_xor(lacc, o);
      }
      u32x4 w0;
      w0.x = pk2bf(p[0], p[1]); w0.y = pk2bf(p[2], p[3]);
      w0.z = pk2bf(p[4], p[5]); w0.w = pk2bf(p[6], p[7]);
      *(u32x4*)&Plds[srow * 36 + i8 * 4] = w0;
      if (i8 == 0) {
        float sc = __expf(mold - mnew);
        mrun[srow] = mnew;
        lrun[srow] = lrun[srow] * sc + ts;
        scal[srow] = sc;
        if (LAB) mka[srow] = mka[srow] * sc + lacc;
      }
    }
    ldsbar();  // B2: Plds + scal RAW (lgkm-only)
    // rescale O (VALU), then PV (MFMA reads oacc as SrcC) using prefetched vreg
#pragma unroll
    for (int mi = 0; mi < 2; ++mi)
#pragma unroll
      for (int r = 0; r < 4; ++r) {
        float sc = scal[mi * 16 + fk * 4 + r];
#pragma unroll
        for (int n = 0; n < 8; ++n) oacc[mi][n][r] *= sc;
      }
    asm volatile("s_nop 7" ::: );  // VALU write -> MFMA SrcC read hazard
#pragma unroll
    for (int kk = 0; kk < 2; ++kk) {
      u32x4 ap0 = *(const u32x4*)&Plds[fr * 36 + kk * 16 + fk * 4];
      u32x4 ap1 = *(const u32x4*)&Plds[(16 + fr) * 36 + kk * 16 + fk * 4];
#pragma unroll
      for (int n = 0; n < 8; ++n) {
        mfma_bf16(oacc[0][n], ap0, vreg[kk][n]);
        mfma_bf16(oacc[1][n], ap1, vreg[kk][n]);
      }
    }
    asm volatile("s_nop 7\n\ts_nop 7" ::: );  // MFMA -> VALU (next rescale/epilogue)
    // no end-of-tile barrier: next Ssm write ordered by B2; next Plds write by B1.
    if (more) {
#pragma unroll
      for (int kk = 0; kk < 4; ++kk) kcur[kk] = knxt[kk];
    }
  }
  asm volatile("s_nop 7\n\ts_nop 7" ::: );
  __syncthreads();  // final full barrier before epilogue
#pragma unroll
  for (int mi = 0; mi < 2; ++mi)
#pragma unroll
    for (int r = 0; r < 4; ++r) {
      int qq = mi * 16 + fk * 4 + r;
      int gq = qt0 + qq;
      if (gq >= kHW) continue;
      float invl = 1.0f / lrun[qq];
      long orow = ((long)img * kR + (long)gq * kB + b) * kD;
#pragma unroll
      for (int n = 0; n < 8; ++n)
        O[orow + wid * 128 + n * 16 + fr] = f2bf(oacc[mi][n][r] * invl);
    }
  if (LAB && tid < 32) {
    int gq = qt0 + tid;
    if (gq < kHW) mkout[(long)img * kR + (long)gq * kB + b] = mka[tid] / lrun[tid];
  }
}

// row += bias; l2-normalize; fp32 in place + bf16 mirror; optional g = u.row
__global__ void k_bias_l2n(float* __restrict__ P, const float* __restrict__ bias, int C,
                           u16b* __restrict__ outb, const float* __restrict__ u,
                           float* __restrict__ g, int L) {
  __shared__ float red[2];
  long row = blockIdx.x;
  float* p = P + row * C;
  int tid = threadIdx.x;  // 128
  int nv = C >> 7;
  float v[4];
  float s = 0.f;
#pragma unroll
  for (int i = 0; i < 4; ++i)
    if (i < nv) {
      float x = p[tid + (i << 7)] + bias[tid + (i << 7)];
      v[i] = x;
      s += x * x;
    }
  s = wsum(s);
  if ((tid & 63) == 0) red[tid >> 6] = s;
  __syncthreads();
  float inv = 1.f / fmaxf(sqrtf(red[0] + red[1]), 1e-12f);
  float dot = 0.f;
#pragma unroll
  for (int i = 0; i < 4; ++i)
    if (i < nv) {
      float x = v[i] * inv;
      p[tid + (i << 7)] = x;
      outb[row * C + tid + (i << 7)] = f2bf(x);
      if (u) dot += x * u[tid + (i << 7)];
    }
  if (u) {
    __syncthreads();
    dot = wsum(dot);
    if ((tid & 63) == 0) red[tid >> 6] = dot;
    __syncthreads();
    if (tid == 0) {
      int img = (int)(row / kR);
      int within = (int)(row % kR);
      int qq = within >> 3, b = within & 7;
      g[((long)(img * 8 + b)) * L + qq] = red[0] + red[1];
    }
  }
}

// generic softmax; optional bf16 out at row*ldo
__global__ __launch_bounds__(256) void k_softmax(float* __restrict__ S, int Lq, int Lk,
                                                 u16b* __restrict__ outb, int ldo) {
  __shared__ float sm[1456];
  __shared__ float red[4];
  int row = blockIdx.x;
  float* Sr = S + (long)row * Lk;
  int tid = threadIdx.x;
  float mx = -3.0e38f;
  for (int k = tid; k < Lk; k += 256) {
    float v = Sr[k] * kTemp;
    sm[k] = v;
    mx = fmaxf(mx, v);
  }
  mx = wmax(mx);
  if ((tid & 63) == 0) red[tid >> 6] = mx;
  __syncthreads();
  mx = fmaxf(fmaxf(red[0], red[1]), fmaxf(red[2], red[3]));
  __syncthreads();
  float s = 0.f;
  for (int k = tid; k < Lk; k += 256) {
    float e = __expf(sm[k] - mx);
    sm[k] = e;
    s += e;
  }
  s = wsum(s);
  if ((tid & 63) == 0) red[tid >> 6] = s;
  __syncthreads();
  float inv = 1.0f / (red[0] + red[1] + red[2] + red[3]);
  for (int k = tid; k < Lk; k += 256) {
    float p = sm[k] * inv;
    if (outb) outb[(long)row * ldo + k] = f2bf(p); else Sr[k] = p;
  }
}

// fused cR + softmax + lab-dot: block z in [0,48)
__global__ __launch_bounds__(256) void k_cwi(const float* __restrict__ vb,
                                             const u16b* __restrict__ Krb,
                                             const float* __restrict__ labv,
                                             float* __restrict__ wI,
                                             float* __restrict__ mki8) {
  __shared__ float sm[kL];
  __shared__ float vbl[kKD];
  __shared__ float red[4];
  int z = blockIdx.x, b = z & 7;
  int tid = threadIdx.x;
  if (tid < kKD) vbl[tid] = vb[(long)z * kKD + tid];
  __syncthreads();
  float mx = -3.0e38f;
  for (int k = tid; k < kL; k += 256) {
    const u16b* kp = Krb + ((long)k * kB + b) * kKD;
    float s = 0.f;
    for (int c = 0; c < kKD; c += 8) {
      u32x4 w = *(const u32x4*)(kp + c);
      s += vbl[c] * bf2f((u16b)(w.x & 0xFFFF)) + vbl[c + 1] * bf2f((u16b)(w.x >> 16));
      s += vbl[c + 2] * bf2f((u16b)(w.y & 0xFFFF)) + vbl[c + 3] * bf2f((u16b)(w.y >> 16));
      s += vbl[c + 4] * bf2f((u16b)(w.z & 0xFFFF)) + vbl[c + 5] * bf2f((u16b)(w.z >> 16));
      s += vbl[c + 6] * bf2f((u16b)(w.w & 0xFFFF)) + vbl[c + 7] * bf2f((u16b)(w.w >> 16));
    }
    sm[k] = s * kTemp;
    mx = fmaxf(mx, sm[k]);
  }
  mx = wmax(mx);
  if ((tid & 63) == 0) red[tid >> 6] = mx;
  __syncthreads();
  mx = fmaxf(fmaxf(red[0], red[1]), fmaxf(red[2], red[3]));
  __syncthreads();
  float s = 0.f;
  for (int k = tid; k < kL; k += 256) {
    float e = __expf(sm[k] - mx);
    sm[k] = e;
    s += e;
  }
  s = wsum(s);
  if ((tid & 63) == 0) red[tid >> 6] = s;
  __syncthreads();
  float inv = 1.0f / (red[0] + red[1] + red[2] + red[3]);
  __syncthreads();
  float dot = 0.f;
  for (int k = tid; k < kL; k += 256) {
    float p = sm[k] * inv;
    wI[(long)z * kL + k] = p;
    dot += p * labv[(long)k * kB + b];
  }
  dot = wsum(dot);
  if ((tid & 63) == 0) red[tid >> 6] = dot;
  __syncthreads();
  if (tid == 0) mki8[z] = red[0] + red[1] + red[2] + red[3];
}

// deterministic rank-1 AV, phase A: row2[(z*8+c)*kD+d] = sum_{k in chunk c} g*seq
__global__ void k_wrowA(const float* __restrict__ g, const float* __restrict__ seq,
                        float* __restrict__ row2) {
  int z = blockIdx.y, img = z >> 3, b = z & 7;
  int c = blockIdx.z;
  int d = blockIdx.x * 128 + threadIdx.x;
  int k0 = c * 61;
  int k1 = min(kHW, k0 + 61);
  float s = 0.f;
  for (int k = k0; k < k1; ++k)
    s += g[(long)z * kHW + k] * seq[((long)img * kR + (long)k * kB + b) * kD + d];
  row2[((long)z * 8 + c) * kD + d] = s;
}

// phase B: row[z*kD+d] = sum_c row2 (fixed order)
__global__ void k_wrowB(const float* __restrict__ row2, float* __restrict__ row) {
  int idx = blockIdx.x * 256 + threadIdx.x;  // 0..48*512
  int z = idx >> 9, d = idx & 511;
  float s = 0.f;
#pragma unroll
  for (int c = 0; c < 8; ++c) s += row2[((long)z * 8 + c) * kD + d];
  row[(long)z * kD + d] = s;
}

// fp32 inorm phase 1 (encoder)
__global__ __launch_bounds__(256) void k_ss1f(const float* __restrict__ A,
                                              const float* __restrict__ B2,
                                              float* __restrict__ part) {
  __shared__ float red[4];
  long r = blockIdx.x;
  int tid = threadIdx.x;
  long base = r * kD;
  float z0 = A[base + tid] + B2[base + tid];
  float z1 = A[base + tid + 256] + B2[base + tid + 256];
  float s = z0 * z0 + z1 * z1;
  s = wsum(s);
  if ((tid & 63) == 0) red[tid >> 6] = s;
  __syncthreads();
  if (tid == 0) part[r] = red[0] + red[1] + red[2] + red[3];
}

// fp32 inorm phase 3 (encoder): fp32 out + bf16 mirror
__global__ __launch_bounds__(256) void k_scale1f(const float* __restrict__ A,
                                                 const float* __restrict__ B2,
                                                 float* __restrict__ outp,
                                                 const float* __restrict__ ss,
                                                 u16b* __restrict__ ob) {
  long r = blockIdx.x;
  int l = (int)(r / kB), b = (int)(r % kB);
  int g = (l / kHW) * kB + b;
  int tid = threadIdx.x;
  float fac = kScaleN * sqrtf(kCnt / (ss[g] + 1e-5f));
  long base = r * kD;
  float x0 = (A[base + tid] + B2[base + tid]) * fac;
  float x1 = (A[base + tid + 256] + B2[base + tid + 256]) * fac;
  outp[base + tid] = x0;
  outp[base + tid + 256] = x1;
  ob[base + tid] = f2bf(x0);
  ob[base + tid + 256] = f2bf(x1);
}

// t1 inorm, phase 1 (B2 bf16)
__global__ __launch_bounds__(256) void k_ss1b(const float* __restrict__ A,
                                              const u16b* __restrict__ B2,
                                              float* __restrict__ part) {
  __shared__ float red[4];
  long r = blockIdx.x;
  int tid = threadIdx.x;
  long base = r * kD;
  float z0 = A[base + tid] + bf2f(B2[base + tid]);
  float z1 = A[base + tid + 256] + bf2f(B2[base + tid + 256]);
  float s = z0 * z0 + z1 * z1;
  s = wsum(s);
  if ((tid & 63) == 0) red[tid >> 6] = s;
  __syncthreads();
  if (tid == 0) part[r] = red[0] + red[1] + red[2] + red[3];
}

__global__ void k_ssred(const float* __restrict__ part, float* __restrict__ ss, int R, int NG) {
  __shared__ float red[8];
  int g = blockIdx.x, v = blockIdx.y;
  int n = g / kB, b = g % kB;
  int tid = threadIdx.x;  // 512
  float s = 0.f;
  for (int p = tid; p < kHW; p += 512) s += part[(long)v * R + ((long)(n * kHW + p) * kB + b)];
  s = wsum(s);
  if ((tid & 63) == 0) red[tid >> 6] = s;
  __syncthreads();
  if (tid == 0) {
    float t = 0.f;
#pragma unroll
    for (int i = 0; i < 8; ++i) t += red[i];
    ss[(long)v * NG + g] = t;
  }
}

// t1 inorm, phase 3 -> bf16 only
__global__ __launch_bounds__(256) void k_scale1b(const float* __restrict__ A,
                                                 const u16b* __restrict__ B2,
                                                 const float* __restrict__ ss,
                                                 u16b* __restrict__ ob) {
  long r = blockIdx.x;
  int img = (int)(r / kR), b = (int)(r & 7);
  int g = img * 8 + b;
  int tid = threadIdx.x;
  float fac = kScaleN * sqrtf(kCnt / (ss[g] + 1e-5f));
  long base = r * kD;
  ob[base + tid] = f2bf((A[base + tid] + bf2f(B2[base + tid])) * fac);
  ob[base + tid + 256] = f2bf((A[base + tid + 256] + bf2f(B2[base + tid + 256])) * fac);
}

// ti8[z,d] = row[z,d] * scale(kHW * ||row||^2)
__global__ void k_ti8(const float* __restrict__ row, float* __restrict__ ti8) {
  __shared__ float red[4];
  int z = blockIdx.x;
  int tid = threadIdx.x;  // 256
  float r0 = row[(long)z * kD + tid], r1 = row[(long)z * kD + tid + 256];
  float s = r0 * r0 + r1 * r1;
  s = wsum(s);
  if ((tid & 63) == 0) red[tid >> 6] = s;
  __syncthreads();
  float ssv = (float)kHW * (red[0] + red[1] + red[2] + red[3]);
  float fac = kScaleN * sqrtf(kCnt / (ssv + 1e-5f));
  ti8[(long)z * kD + tid] = r0 * fac;
  ti8[(long)z * kD + tid + 256] = r1 * fac;
}

// vb[z,:] = l2n(ti8_z @ WkC + bkC)
__global__ void k_vb(const float* __restrict__ ti8, const float* __restrict__ Wk,
                     const float* __restrict__ bk, float* __restrict__ vb) {
  __shared__ float part[4][128];
  __shared__ float red[2];
  int z = blockIdx.x;
  int j = threadIdx.x;
  int dz = threadIdx.y;
  const float* row = ti8 + (long)z * kD;
  float acc = 0.f;
  int d0 = dz * 128;
  for (int d = d0; d < d0 + 128; ++d) acc += row[d] * Wk[(long)d * kKD + j];
  part[dz][j] = acc;
  __syncthreads();
  if (dz == 0) {
    float a = part[0][j] + part[1][j] + part[2][j] + part[3][j] + bk[j];
    float s = a * a;
    s = wsum(s);
    if ((j & 63) == 0) red[j >> 6] = s;
    part[0][j] = a;
  }
  __syncthreads();
  if (dz == 0) {
    float inv = 1.f / fmaxf(sqrtf(red[0] + red[1]), 1e-12f);
    vb[(long)z * kKD + j] = part[0][j] * inv;
  }
}

// ci8[z,d] = sum_l wI[z,l] * VrT[b][d][l]
__global__ void k_ci8(const float* __restrict__ wI, const u16b* __restrict__ VrT,
                      float* __restrict__ ci8) {
  int idx = blockIdx.x * 4 + (threadIdx.x >> 6);
  int z = idx >> 9, d = idx & 511;
  int b = z & 7;
  int lane = threadIdx.x & 63;
  const float* w = wI + (long)z * kL;
  const u16b* vt = VrT + ((long)b * kD + d) * kLp;
  float s = 0.f;
  for (int l = lane; l < kL; l += 64) s += w[l] * bf2f(vt[l]);
  s = wsum(s);
  if (lane == 0) ci8[(long)z * kD + d] = s;
}

// tail partials: v in {a^2, b^2, ab}, a = t1*mk, b = t1 + c3 (bf16 inputs)
__global__ __launch_bounds__(256) void k_ss3b(const u16b* __restrict__ t1b,
                                              const float* __restrict__ mkr,
                                              const u16b* __restrict__ c3b,
                                              float* __restrict__ part) {
  __shared__ float red[4][3];
  long r = blockIdx.x;
  int tid = threadIdx.x;
  long base = r * kD;
  float mk = mkr[r];
  float s0 = 0.f, s1 = 0.f, s2 = 0.f;
#pragma unroll
  for (int j = 0; j < 2; ++j) {
    int d = tid + j * 256;
    float t = bf2f(t1b[base + d]);
    float a = t * mk;
    float bb = t + bf2f(c3b[base + d]);
    s0 += a * a; s1 += bb * bb; s2 += a * bb;
  }
  int w = tid >> 6, lane = tid & 63;
  float t0 = wsum(s0), t1 = wsum(s1), t2 = wsum(s2);
  if (lane == 0) { red[w][0] = t0; red[w][1] = t1; red[w][2] = t2; }
  __syncthreads();
  if (tid < 3)
    part[(long)tid * kR6 + r] = red[0][tid] + red[1][tid] + red[2][tid] + red[3][tid];
}

// per-image coefficients + oi8 (imag analytic)
__global__ __launch_bounds__(512) void k_coef(const float* __restrict__ ssp,
                                              const float* __restrict__ ti8,
                                              const float* __restrict__ ci8,
                                              const float* __restrict__ mki8,
                                              float* __restrict__ coef,
                                              float* __restrict__ oi8) {
  __shared__ float cai[8], cbi[8];
  int img = blockIdx.x;
  int tid = threadIdx.x;
  int b = tid >> 6, lane = tid & 63;
  int z = img * 8 + b;
  float sT = 0.f, sU = 0.f, sV = 0.f;
  for (int d = lane; d < kD; d += 64) {
    float ti = ti8[(long)z * kD + d], ci = ci8[(long)z * kD + d];
    float u = ti + ci;
    sT += ti * ti; sU += u * u; sV += ti * u;
  }
  sT = wsum(sT); sU = wsum(sU); sV = wsum(sV);
  if (lane == 0) {
    float SSa = ssp[z], SSb = ssp[48 + z], SSab = ssp[96 + z];
    float f2 = kScaleN * sqrtf(kCnt / (SSa + 1e-5f));
    float f4 = kScaleN * sqrtf(kCnt / (SSb + 1e-5f));
    float ssz = f2 * f2 * SSa + f4 * f4 * SSb + 2.f * f2 * f4 * SSab;
    float fac = kScaleN * sqrtf(kCnt / (ssz + 1e-5f));
    coef[img * 16 + b] = f2 * fac;
    coef[img * 16 + 8 + b] = f4 * fac;
    float mk = mki8[z];
    float SSai = (float)kHW * mk * mk * sT;
    float SSbi = (float)kHW * sU;
    float SSabi = (float)kHW * mk * sV;
    float f2i = kScaleN * sqrtf(kCnt / (SSai + 1e-5f));
    float f4i = kScaleN * sqrtf(kCnt / (SSbi + 1e-5f));
    float sszi = f2i * f2i * SSai + f4i * f4i * SSbi + 2.f * f2i * f4i * SSabi;
    float faci = kScaleN * sqrtf(kCnt / (sszi + 1e-5f));
    cai[b] = f2i * faci;
    cbi[b] = f4i * faci;
  }
  __syncthreads();
#pragma unroll
  for (int j = 0; j < 8; ++j) {
    int i = tid * 8 + j;
    int bb = i >> 9, d = i & 511;
    int zz = img * 8 + bb;
    float ti = ti8[(long)zz * kD + d], ci = ci8[(long)zz * kD + d];
    oi8[(long)img * 4096 + i] = ti * mki8[zz] * cai[bb] + (ti + ci) * cbi[bb];
  }
}

// oadd[img][o*8+b] = Wc_imag_row(o) . oi8[img*8+b]
__global__ void k_oadd(const float* __restrict__ Wc, const float* __restrict__ oi8,
                       float* __restrict__ oadd) {
  int idx = blockIdx.x * 4 + (threadIdx.x >> 6);
  int img = idx >> 12, rem = idx & 4095;
  int o = rem >> 3, b = rem & 7;
  int lane = threadIdx.x & 63;
  const float* wrow = Wc + (long)o * 1024 + 512;
  const float* oi = oi8 + (long)img * 4096 + (long)b * kD;
  float s = 0.f;
  for (int d = lane; d < kD; d += 64) s += wrow[d] * oi[d];
  s = wsum(s);
  if (lane == 0) oadd[(long)img * 4096 + o * 8 + b] = s;
}

// t2b[r][d] = bf16( t1*mk*ca + (t1+c3)*cb )
__global__ __launch_bounds__(256) void k_zfinb(const u16b* __restrict__ t1b,
                                               const float* __restrict__ mkr,
                                               const u16b* __restrict__ c3b,
                                               const float* __restrict__ coef,
                                               u16b* __restrict__ t2b) {
  long r = blockIdx.x;
  int img = (int)(r / kR), b = (int)(r & 7);
  int tid = threadIdx.x;
  float mk = mkr[r];
  float ca = coef[img * 16 + b], cb = coef[img * 16 + 8 + b];
  long base = r * kD;
#pragma unroll
  for (int j = 0; j < 2; ++j) {
    int d = tid + j * 256;
    float t = bf2f(t1b[base + d]);
    float ov = t * mk * ca + (t + bf2f(c3b[base + d])) * cb;
    t2b[base + d] = f2bf(ov);
  }
}

template <int BM, int BN, bool AF32, bool ACC>
void gemm(hipStream_t s, const void* A, const u16b* B, float* C, int M, int N, int K, int lda,
          int ldb, int ldc, long sA1, long sA2, long sB1, long sB2, long sC1, long sC2,
          int batch, const float* addv = nullptr) {
  dim3 grd(CDIV(N, BN), CDIV(M, BM), batch), blk(256);
  k_gemm<BM, BN, AF32, ACC><<<grd, blk, 0, s>>>(A, B, C, M, N, K, lda, ldb, ldc, sA1, sA2,
                                                sB1, sB2, sC1, sC2, addv);
}

}  // namespace

extern "C" void kernel_launch(void* const* d_in, const int* in_sizes, int n_in, void* d_out,
                              int out_size, void* d_ws, size_t ws_size, hipStream_t stream) {
  (void)in_sizes; (void)n_in; (void)out_size;
  const float* tf  = (const float*)d_in[0];
  const float* sf  = (const float*)d_in[1];
  const float* tl  = (const float*)d_in[2];
  const float* WkE = (const float*)d_in[3];
  const float* bkE = (const float*)d_in[4];
  const float* WkS = (const float*)d_in[5];
  const float* bkS = (const float*)d_in[6];
  const float* WkC = (const float*)d_in[7];
  const float* bkC = (const float*)d_in[8];
  const float* Wc  = (const float*)d_in[9];
  float* out = (float*)d_out;
  float* ws = (float*)d_ws;

  const long LBD = (long)kL * kB * kD;
  const long LBK = (long)kL * kB * kKD;

  long off = 0;
  auto alloc = [&](long n) { long o = off; off += (n + 255) & ~255L; return o; };
  auto allocU = [&](long nu) { return alloc((nu + 1) / 2); };

  long o_seqT = alloc(LBD);
  long o_seqS = alloc(LBD);
  long o_Kr   = alloc(LBK);
  long o_Krb  = allocU(LBK);
  long o_VrT  = allocU((long)kB * kD * kLp);
  long o_tfb  = allocU((long)kNI * kB * kD * kHWp);
  long o_sfb  = allocU((long)kNI * kB * kD * kHWp);
  long o_WkTE = allocU((long)kD * kD);
  long o_WkTS = allocU((long)kKD * kD);
  long o_WkTC = allocU((long)kKD * kD);
  long o_Wcb  = allocU((long)kD * 2 * kD);
  long o_lab  = alloc((long)kL * kB);
  long o_uS   = alloc(kKD);
  long o_vb   = alloc(48L * kKD);
  long o_g    = alloc(48L * kHW);
  long o_wI   = alloc(48L * kL);
  long o_row  = alloc(48L * kD);
  long o_row2 = alloc(48L * 8 * kD);
  long o_mkr  = alloc((long)kR6);
  long o_mki8 = alloc(48);
  long o_ti8  = alloc(48L * kD);
  long o_ci8  = alloc(48L * kD);
  long o_oi8  = alloc(48L * kD);
  long o_oadd = alloc(6L * kD * 8);
  long o_ss   = alloc(512);
  long o_part = alloc(3L * kR6);
  long o_scr  = off;

  // encoder overlay
  long o_Pe  = o_scr;
  long o_Peb = o_Pe + LBD;
  long o_Ae  = o_Peb + LBD / 2;
  long o_Aeb = o_Ae + (long)kB * kL * kL;
  long enc_end = o_Aeb + (8L * kL * kLp + 1) / 2;
  long o_ar  = o_Pe;   // after Pe dead
  long o_mr  = o_Ae;   // after Ae dead

  // decoder overlay (batched over 6 images)
  long p = o_scr;
  auto nxt = [&](long n) { long o = p; p += (n + 255) & ~255L; return o; };
  long o_Ps   = nxt((long)kR6 * kKD);
  long o_Psb  = nxt(((long)kR6 * kKD + 1) / 2);
  long o_Pcb  = nxt(((long)kR6 * kKD + 1) / 2);
  long o_s2rb = nxt(((long)kR6 * kD + 1) / 2);
  long o_t1rb = nxt(((long)kR6 * kD + 1) / 2);
  long o_c3rb = nxt(((long)kR6 * kD + 1) / 2);
  long o_t2b  = nxt(((long)kR6 * kD + 1) / 2);
  long img_end = p;

  long total = (enc_end > img_end ? enc_end : img_end);
  if ((size_t)total * sizeof(float) > ws_size) return;

  float* seqT = ws + o_seqT;
  float* Kr = ws + o_Kr;
  u16b* Krb = (u16b*)(ws + o_Krb);
  u16b* VrT = (u16b*)(ws + o_VrT);
  u16b* tfb = (u16b*)(ws + o_tfb);
  float* lab = ws + o_lab;
  float* uS = ws + o_uS;
  float* vb = ws + o_vb;
  float* g_ = ws + o_g;
  float* wI = ws + o_wI;
  float* row = ws + o_row;
  float* row2 = ws + o_row2;
  float* mkr = ws + o_mkr;
  float* mki8 = ws + o_mki8;
  float* ti8 = ws + o_ti8;
  float* ci8 = ws + o_ci8;
  float* oi8 = ws + o_oi8;
  float* oadd = ws + o_oadd;
  float* ssp = ws + o_ss;
  float* coef = ssp + 160;
  float* part = ws + o_part;
  float* Pe = ws + o_Pe;
  u16b* Peb = (u16b*)(ws + o_Peb);
  float* Ae = ws + o_Ae;
  u16b* Aeb = (u16b*)(ws + o_Aeb);
  float* ar = ws + o_ar;
  float* mr = ws + o_mr;
  u16b* mrb = (u16b*)(ws + o_mr + LBD);
  float* Ps = ws + o_Ps;
  u16b* Psb = (u16b*)(ws + o_Psb);
  u16b* Pcb = (u16b*)(ws + o_Pcb);
  u16b* s2rb = (u16b*)(ws + o_s2rb);
  u16b* t1rb = (u16b*)(ws + o_t1rb);
  u16b* c3rb = (u16b*)(ws + o_c3rb);
  u16b* t2b = (u16b*)(ws + o_t2b);
  u16b* WkTE = (u16b*)(ws + o_WkTE);
  u16b* WkTS = (u16b*)(ws + o_WkTS);
  u16b* WkTC = (u16b*)(ws + o_WkTC);
  u16b* Wcb = (u16b*)(ws + o_Wcb);

  // ---- stage 0 ----
  {
    dim3 grd(CDIV(kHW, 32), CDIV(kD, 32), kNI * kB), blk(32, 8);
    k_toseq<<<grd, blk, 0, stream>>>(tf, seqT);
    k_toseq<<<grd, blk, 0, stream>>>(sf, ws + o_seqS);
  }
  k_cvt2d<<<kNI * kB * kD, 256, 0, stream>>>(tf, tfb, kHW, kHWp);
  k_cvt2d<<<kNI * kB * kD, 256, 0, stream>>>(sf, (u16b*)(ws + o_sfb), kHW, kHWp);
  k_cvt2d<<<kD, 256, 0, stream>>>(Wc, Wcb, 2 * kD, 2 * kD);
  k_tcvt<<<dim3(kD / 32, kD / 32), dim3(32, 8), 0, stream>>>(WkE, WkTE, kD, kD);
  k_tcvt<<<dim3(kKD / 32, kD / 32), dim3(32, 8), 0, stream>>>(WkS, WkTS, kD, kKD);
  k_tcvt<<<dim3(kKD / 32, kD / 32), dim3(32, 8), 0, stream>>>(WkC, WkTC, kD, kKD);
  k_lab<<<CDIV(kNI * kB * kHW, 256), 256, 0, stream>>>(tl, lab);
  k_l2n_vec<<<1, 128, 0, stream>>>(bkS, uS, kKD);

  // ---- encoder (imag branch dead) ----
  gemm<64, 128, true, false>(stream, seqT, WkTE, Pe, kL * kB, kD, kD, kD, kD, kD,
                             0, 0, 0, 0, 0, 0, 1);
  k_bias_l2n<<<kL * kB, 128, 0, stream>>>(Pe, bkE, kD, Peb, nullptr, nullptr, 0);
  gemm<128, 128, false, false>(stream, Peb, Peb, Ae, kL, kL, kD, kB * kD, kB * kD, kL,
                               0, kD, 0, kD, 0, (long)kL * kL, 8);
  k_softmax<<<kB * kL, 256, 0, stream>>>(Ae, kL, kL, Aeb, kLp);
  gemm<64, 128, false, false>(stream, Aeb, tfb, ar, kL, kD, kHW, kLp, kHWp, kB * kD,
                              0, (long)kL * kLp, 0, (long)kD * kHWp, 0, kD, 8);
  gemm<64, 128, false, true>(stream, Aeb + kHW, tfb + (long)kB * kD * kHWp, ar, kL, kD, kHW,
                             kLp, kHWp, kB * kD, 0, (long)kL * kLp, 0, (long)kD * kHWp, 0, kD,
                             8);
  gemm<64, 128, false, true>(stream, Aeb + 2 * kHW, tfb + 2L * kB * kD * kHWp, ar, kL, kD,
                             kHW, kLp, kHWp, kB * kD, 0, (long)kL * kLp, 0, (long)kD * kHWp,
                             0, kD, 8);
  // mem_r = inorm(seqT + ar)
  k_ss1f<<<kL * kB, 256, 0, stream>>>(seqT, ar, part);
  k_ssred<<<dim3(kNI * kB, 1), 512, 0, stream>>>(part, ssp, kL * kB, kNI * kB);
  k_scale1f<<<kL * kB, 256, 0, stream>>>(seqT, ar, mr, ssp, mrb);
  k_vrt<<<dim3(CDIV(kL, 32), kD / 32, kB), dim3(32, 8), 0, stream>>>(mr, lab, VrT);
  gemm<64, 64, false, false>(stream, mrb, WkTC, Kr, kL * kB, kKD, kD, kD, kD, kKD,
                             0, 0, 0, 0, 0, 0, 1);
  k_bias_l2n<<<kL * kB, 128, 0, stream>>>(Kr, bkC, kKD, Krb, nullptr, nullptr, 0);

  // ---- decoder (fully batched over 48 = 6 img x 8 b) ----
  gemm<64, 128, true, false>(stream, seqT, WkTS, Ps, kR6, kKD, kD, kD, kD, kKD,
                             0, 0, 0, 0, 0, 0, 1);
  k_bias_l2n<<<kR6, 128, 0, stream>>>(Ps, bkS, kKD, Psb, uS, g_, kHW);
  k_softmax<<<48, 256, 0, stream>>>(g_, 1, kHW, nullptr, 0);  // wi rows
  k_wrowA<<<dim3(kD / 128, 48, 8), 128, 0, stream>>>(g_, seqT, row2);
  k_wrowB<<<48 * kD / 256, 256, 0, stream>>>(row2, row);
  k_ti8<<<48, 256, 0, stream>>>(row, ti8);
  k_vb<<<48, dim3(128, 4), 0, stream>>>(ti8, WkC, bkC, vb);
  // self-attention flash: s2r
  k_flash<false, true, true><<<768, 256, 0, stream>>>(Psb, Psb, tfb, nullptr, s2rb,
                                                      nullptr, kHW, kHWp);
  // t1r = inorm(t + s2r) -> bf16
  k_ss1b<<<kR6, 256, 0, stream>>>(seqT, s2rb, part);
  k_ssred<<<dim3(48, 1), 512, 0, stream>>>(part, ssp, kR6, 48);
  k_scale1b<<<kR6, 256, 0, stream>>>(seqT, s2rb, ssp, t1rb);
  // cross projection
  gemm<64, 128, false, false>(stream, t1rb, WkTC, Ps, kR6, kKD, kD, kD, kD, kKD,
                              0, 0, 0, 0, 0, 0, 1);
  k_bias_l2n<<<kR6, 128, 0, stream>>>(Ps, bkC, kKD, Pcb, nullptr, nullptr, 0);
  // imag branch (q-independent)
  k_cwi<<<48, 256, 0, stream>>>(vb, Krb, lab, wI, mki8);
  k_ci8<<<48 * 512 / 4, 256, 0, stream>>>(wI, VrT, ci8);
  // cross flash: c3r + mkr
  k_flash<true, false, false><<<768, 256, 0, stream>>>(Pcb, Krb, VrT, lab, c3rb,
                                                       mkr, kL, kLp);
  // fused tail
  k_ss3b<<<kR6, 256, 0, stream>>>(t1rb, mkr, c3rb, part);
  k_ssred<<<dim3(48, 3), 512, 0, stream>>>(part, ssp, kR6, 48);
  k_coef<<<6, 512, 0, stream>>>(ssp, ti8, ci8, mki8, coef, oi8);
  k_oadd<<<6 * 4096 / 4, 256, 0, stream>>>(Wc, oi8, oadd);
  k_zfinb<<<kR6, 256, 0, stream>>>(t1rb, mkr, c3rb, coef, t2b);
  // 1x1 conv: batch 48, K=512 real + rank-1 imag epilogue
  gemm<64, 64, false, false>(stream, Wcb, t2b, out, kD, kHW, kD, 2 * kD, kB * kD, kHW,
                             0, 0, (long)kR * kD, kD, 8L * kD * kHW, (long)kD * kHW, 48, oadd);
}

// Round 18
// 771.672 us; speedup vs baseline: 1.0496x; 1.0496x over previous
//
#include <hip/hip_runtime.h>

// ComTransformer on MI355X — round 18: V panel-repack for request-coalesced PV.
//  - flash PV V-loads were 16 L2-requests/instr (16 lanes x 16B at 2.9KB stride).
//    V repacked to 8-col panels V8[z][c8][d][8]: 16 lanes read consecutive d ->
//    256B contiguous per fk group = 4 requests/instr (16x fewer). L2-request-rate
//    was the flash bottleneck (all blocks resident; swizzle/prefetch both null).
//  - s_setprio(1) around flash MFMA clusters (T5).
// Prior: lgkm-only flash barriers, XCD-local flash grid, batched decoder, rank-1
// imag collapse, pipelined BK=64 bf16 NT GEMM + XCD swizzle.

namespace {

constexpr int kNI = 3;
constexpr int kB  = 8;
constexpr int kD  = 512;
constexpr int kKD = 128;
constexpr int kHW = 484;
constexpr int kL  = kNI * kHW;  // 1452
constexpr int kLp = 1456;
constexpr int kHWp = 488;
constexpr float kTemp = 30.0f;
constexpr float kCnt  = 247808.0f;
constexpr float kScaleN = 0.011048543456039806f;
constexpr int kR = kHW * kB;   // 3872 rows per image
constexpr int kR6 = 6 * kR;    // 23232
constexpr int kP8s = kHWp / 8;   // 61 panels (self V)
constexpr int kP8c = kLp / 8;    // 182 panels (cross V)

#define CDIV(a, b) (((a) + (b) - 1) / (b))

typedef float f32x4 __attribute__((ext_vector_type(4)));
typedef unsigned int u32x4 __attribute__((ext_vector_type(4)));
typedef unsigned short u16b;

__device__ __forceinline__ float wsum(float v) {
#pragma unroll
  for (int o = 32; o; o >>= 1) v += __shfl_down(v, o);
  return v;
}
__device__ __forceinline__ float wmax(float v) {
#pragma unroll
  for (int o = 32; o; o >>= 1) v = fmaxf(v, __shfl_down(v, o));
  return v;
}

__device__ __forceinline__ unsigned pk2bf(float lo, float hi) {
  union { float f; unsigned u; } a, b;
  a.f = lo; b.f = hi;
  unsigned ra = (a.u + 0x7FFFu + ((a.u >> 16) & 1u)) >> 16;
  unsigned rb = (b.u + 0x7FFFu + ((b.u >> 16) & 1u)) >> 16;
  return (ra & 0xFFFFu) | (rb << 16);
}
__device__ __forceinline__ u16b f2bf(float x) {
  union { float f; unsigned u; } a;
  a.f = x;
  return (u16b)((a.u + 0x7FFFu + ((a.u >> 16) & 1u)) >> 16);
}
__device__ __forceinline__ float bf2f(u16b x) {
  union { unsigned u; float f; } a;
  a.u = (unsigned)x << 16;
  return a.f;
}

__device__ __forceinline__ void mfma_bf16(f32x4& d, const u32x4& a, const u32x4& b) {
  asm("v_mfma_f32_16x16x32_bf16 %0, %1, %2, %0" : "+v"(d) : "v"(a), "v"(b));
}

// LDS-only barrier (global loads stay in flight across it)
__device__ __forceinline__ void ldsbar() {
  asm volatile("s_waitcnt lgkmcnt(0)" ::: "memory");
  __builtin_amdgcn_s_barrier();
  asm volatile("" ::: "memory");
}

// ---------------- layout transform: [n,b,d,hw] -> seq [(n*hw),b,d] fp32 -----------
__global__ void k_toseq(const float* __restrict__ in, float* __restrict__ out) {
  __shared__ float tile[32][33];
  int nb = blockIdx.z;
  int n = nb / kB, b = nb % kB;
  int p0 = blockIdx.x * 32, d0 = blockIdx.y * 32;
  int tx = threadIdx.x, ty = threadIdx.y;
#pragma unroll
  for (int j = 0; j < 4; ++j) {
    int d = d0 + ty + j * 8, p = p0 + tx;
    if (d < kD && p < kHW) tile[ty + j * 8][tx] = in[(long)nb * kD * kHW + (long)d * kHW + p];
  }
  __syncthreads();
#pragma unroll
  for (int j = 0; j < 4; ++j) {
    int p = p0 + ty + j * 8, d = d0 + tx;
    if (p < kHW && d < kD)
      out[((long)(n * kHW + p) * kB + b) * kD + d] = tile[tx][ty + j * 8];
  }
}

__global__ void k_cvt2d(const float* __restrict__ in, u16b* __restrict__ out, int C, int Cp) {
  long r = blockIdx.x;
  for (int c = threadIdx.x; c < C; c += 256)
    out[r * Cp + c] = f2bf(in[r * (long)C + c]);
}

__global__ void k_tcvt(const float* __restrict__ in, u16b* __restrict__ out, int R, int C) {
  __shared__ float tile[32][33];
  int c0 = blockIdx.x * 32, r0 = blockIdx.y * 32;
  int tx = threadIdx.x, ty = threadIdx.y;
#pragma unroll
  for (int j = 0; j < 4; ++j) {
    int r = r0 + ty + j * 8, c = c0 + tx;
    if (r < R && c < C) tile[ty + j * 8][tx] = in[(long)r * C + c];
  }
  __syncthreads();
#pragma unroll
  for (int j = 0; j < 4; ++j) {
    int c = c0 + ty + j * 8, r = r0 + tx;
    if (r < R && c < C) out[(long)c * R + r] = f2bf(tile[tx][ty + j * 8]);
  }
}

// VrT[b][d][l] = bf16( mr[(l,b),d] * lab[l,b] ), stride kLp
__global__ void k_vrt(const float* __restrict__ mr, const float* __restrict__ lab,
                      u16b* __restrict__ vt) {
  __shared__ float tile[32][33];
  int l0 = blockIdx.x * 32, d0 = blockIdx.y * 32, b = blockIdx.z;
  int tx = threadIdx.x, ty = threadIdx.y;
#pragma unroll
  for (int j = 0; j < 4; ++j) {
    int l = l0 + ty + j * 8;
    if (l < kL)
      tile[ty + j * 8][tx] = mr[((long)l * kB + b) * kD + d0 + tx] * lab[(long)l * kB + b];
  }
  __syncthreads();
#pragma unroll
  for (int j = 0; j < 4; ++j) {
    int d = d0 + ty + j * 8, l = l0 + tx;
    if (l < kL) vt[((long)b * kD + d) * kLp + l] = f2bf(tile[tx][ty + j * 8]);
  }
}

// pack V [Z][kD][ldv] -> V8 [Z][P][kD][8]; pad cols (>= Sreal) zero-filled
__global__ void k_vpack(const u16b* __restrict__ in, u16b* __restrict__ out,
                        int ldv, int P, int Sreal) {
  long idx = (long)blockIdx.x * 256 + threadIdx.x;
  int j = (int)(idx & 7);
  int d = (int)((idx >> 3) & 511);
  long t = idx >> 12;
  int c8 = (int)(t % P);
  int z = (int)(t / P);
  int col = c8 * 8 + j;
  u16b v = (col < Sreal) ? in[((long)z * kD + d) * ldv + col] : (u16b)0;
  out[idx] = v;
}

__global__ void k_lab(const float* __restrict__ tl, float* __restrict__ lab) {
  long i = (long)blockIdx.x * 256 + threadIdx.x;
  const long tot = (long)kNI * kB * kHW;
  if (i >= tot) return;
  int p = (int)(i % kHW);
  long t = i / kHW;
  int b = (int)(t % kB);
  int n = (int)(t / kB);
  lab[(long)(n * kHW + p) * kB + b] = tl[i];
}

__global__ void k_l2n_vec(const float* __restrict__ src, float* __restrict__ u, int C) {
  __shared__ float red[2];
  int tid = threadIdx.x;  // 128
  float s = 0.f;
  for (int c = tid; c < C; c += 128) { float x = src[c]; s += x * x; }
  s = wsum(s);
  if ((tid & 63) == 0) red[tid >> 6] = s;
  __syncthreads();
  float inv = 1.f / fmaxf(sqrtf(red[0] + red[1]), 1e-12f);
  for (int c = tid; c < C; c += 128) u[c] = src[c] * inv;
}

// ---------------- pipelined NT bf16 MFMA GEMM (XCD swizzle, 2-stride batch) -------
template <int BM, int BN, bool AF32, bool ACC>
__global__ __launch_bounds__(256) void k_gemm(const void* Ap, const u16b* __restrict__ B,
                                              float* __restrict__ C, int M, int N, int K,
                                              int lda, int ldb, int ldc,
                                              long sA1, long sA2, long sB1, long sB2,
                                              long sC1, long sC2,
                                              const float* __restrict__ addv) {
  const int gx = gridDim.x, gy = gridDim.y;
  const int nwg = gx * gy * gridDim.z;
  const int orig = (blockIdx.z * gy + blockIdx.y) * gx + blockIdx.x;
  const int q = nwg >> 3, rr = nwg & 7, xcd = orig & 7, idx = orig >> 3;
  const int swz = (xcd < rr ? xcd * (q + 1) : rr * (q + 1) + (xcd - rr) * q) + idx;
  const int bx = swz % gx;
  const int tmp = swz / gx;
  const int by = tmp % gy, bz = tmp / gy;
  const int za = bz >> 3, zb = bz & 7;

  const char* Ab = (const char*)Ap + (za * sA1 + zb * sA2) * (AF32 ? 4 : 2);
  const u16b* Bb = B + za * sB1 + zb * sB2;
  C += za * sC1 + zb * sC2;
  constexpr int FM = BM / 32, FN = BN / 32;
  constexpr int NSA = BM * 8 / 256;
  constexpr int NSB = BN * 8 / 256;
  const int m0 = by * BM, n0 = bx * BN;
  const int tid = threadIdx.x;
  const int wid = tid >> 6, lane = tid & 63;
  const int wr = wid >> 1, wc = wid & 1;
  const int fr = lane & 15, fk = lane >> 4;

  __shared__ unsigned AsU[BM * 36];
  __shared__ unsigned BsU[BN * 36];
  f32x4 acc[FM][FN] = {};

  u32x4 pa[NSA];
  float4 paf[AF32 ? 2 * NSA : 1];
  u32x4 pb[NSB];

  auto loadA = [&](int k0) {
#pragma unroll
    for (int i = 0; i < NSA; ++i) {
      int si = tid + i * 256;
      int row = si >> 3, c = si & 7;
      int gr = m0 + row, gk = k0 + c * 8;
      if constexpr (AF32) {
        const float* A = (const float*)Ab;
        if (gr < M && gk + 8 <= K) {
          const float* ap = A + (long)gr * lda + gk;
          paf[2 * i] = *(const float4*)ap;
          paf[2 * i + 1] = *(const float4*)(ap + 4);
        } else {
          float v[8];
#pragma unroll
          for (int j = 0; j < 8; ++j)
            v[j] = (gr < M && gk + j < K) ? A[(long)gr * lda + gk + j] : 0.f;
          paf[2 * i] = make_float4(v[0], v[1], v[2], v[3]);
          paf[2 * i + 1] = make_float4(v[4], v[5], v[6], v[7]);
        }
      } else {
        const u16b* A = (const u16b*)Ab;
        if (gr < M && gk + 8 <= K) {
          pa[i] = *(const u32x4*)(A + (long)gr * lda + gk);
        } else {
          unsigned v[8];
#pragma unroll
          for (int j = 0; j < 8; ++j)
            v[j] = (gr < M && gk + j < K) ? A[(long)gr * lda + gk + j] : 0u;
          pa[i].x = v[0] | (v[1] << 16); pa[i].y = v[2] | (v[3] << 16);
          pa[i].z = v[4] | (v[5] << 16); pa[i].w = v[6] | (v[7] << 16);
        }
      }
    }
  };
  auto loadB = [&](int k0) {
#pragma unroll
    for (int i = 0; i < NSB; ++i) {
      int si = tid + i * 256;
      int row = si >> 3, c = si & 7;
      int gr = n0 + row, gk = k0 + c * 8;
      if (gr < N && gk + 8 <= K) {
        pb[i] = *(const u32x4*)(Bb + (long)gr * ldb + gk);
      } else {
        unsigned v[8];
#pragma unroll
        for (int j = 0; j < 8; ++j)
          v[j] = (gr < N && gk + j < K) ? Bb[(long)gr * ldb + gk + j] : 0u;
        pb[i].x = v[0] | (v[1] << 16); pb[i].y = v[2] | (v[3] << 16);
        pb[i].z = v[4] | (v[5] << 16); pb[i].w = v[6] | (v[7] << 16);
      }
    }
  };
  auto storeAB = [&]() {
#pragma unroll
    for (int i = 0; i < NSA; ++i) {
      int si = tid + i * 256;
      int row = si >> 3, c = si & 7;
      u32x4 w;
      if constexpr (AF32) {
        float4 u0 = paf[2 * i], u1 = paf[2 * i + 1];
        w.x = pk2bf(u0.x, u0.y); w.y = pk2bf(u0.z, u0.w);
        w.z = pk2bf(u1.x, u1.y); w.w = pk2bf(u1.z, u1.w);
      } else {
        w = pa[i];
      }
      *(u32x4*)&AsU[row * 36 + c * 4] = w;
    }
#pragma unroll
    for (int i = 0; i < NSB; ++i) {
      int si = tid + i * 256;
      int row = si >> 3, c = si & 7;
      *(u32x4*)&BsU[row * 36 + c * 4] = pb[i];
    }
  };

  loadA(0);
  loadB(0);
  storeAB();
  __syncthreads();
  const int nk = CDIV(K, 64);
  for (int t = 0; t < nk; ++t) {
    const bool more = (t + 1 < nk);
    if (more) { loadA((t + 1) * 64); loadB((t + 1) * 64); }
#pragma unroll
    for (int kk = 0; kk < 2; ++kk) {
      u32x4 af[FM], bf[FN];
#pragma unroll
      for (int mi = 0; mi < FM; ++mi)
        af[mi] = *(const u32x4*)&AsU[(wr * (BM / 2) + mi * 16 + fr) * 36 + kk * 16 + fk * 4];
#pragma unroll
      for (int ni = 0; ni < FN; ++ni)
        bf[ni] = *(const u32x4*)&BsU[(wc * (BN / 2) + ni * 16 + fr) * 36 + kk * 16 + fk * 4];
#pragma unroll
      for (int mi = 0; mi < FM; ++mi)
#pragma unroll
        for (int ni = 0; ni < FN; ++ni) mfma_bf16(acc[mi][ni], af[mi], bf[ni]);
    }
    if (more) {
      __syncthreads();
      storeAB();
      __syncthreads();
    }
  }
  asm volatile("s_nop 7\n\ts_nop 7" ::: );
#pragma unroll
  for (int mi = 0; mi < FM; ++mi) {
#pragma unroll
    for (int r = 0; r < 4; ++r) {
      int gm = m0 + wr * (BM / 2) + mi * 16 + fk * 4 + r;
      if (gm >= M) continue;
      float av = addv ? addv[(long)za * (kD * 8) + (long)gm * 8 + zb] : 0.f;
#pragma unroll
      for (int ni = 0; ni < FN; ++ni) {
        int gn = n0 + wc * (BN / 2) + ni * 16 + fr;
        if (gn >= N) continue;
        long idx2 = (long)gm * ldc + gn;
        float v = acc[mi][ni][r] + av;
        C[idx2] = ACC ? (C[idx2] + v) : v;
      }
    }
  }
}

// ---------------- flash attention: O = softmax(30 Q K^T) V, optional lab-dot ------
// 1-D grid, b = blockIdx.x & 7 (XCD-local K/V). V in 8-col panels [Z][P][kD][8]:
// PV loads are 256B-contiguous per fk group. V reg-prefetch, K dbuf, lgkm barriers.
template <bool LAB, bool KIMG, bool VZ>
__global__ __launch_bounds__(256) void k_flash(const u16b* __restrict__ Q,
                                               const u16b* __restrict__ K,
                                               const u16b* __restrict__ V8,
                                               const float* __restrict__ labv,
                                               u16b* __restrict__ O,
                                               float* __restrict__ mkout,
                                               int S, int P8) {
  int orig = blockIdx.x;
  int b = orig & 7;
  int t = orig >> 3;
  int qt0 = (t & 15) * 32;
  int img = t >> 4;
  int z = img * 8 + b;
  int tid = threadIdx.x, wid = tid >> 6, lane = tid & 63;
  int fr = lane & 15, fk = lane >> 4;

  __shared__ float Ssm[32 * 68];
  __shared__ unsigned Plds[32 * 36];
  __shared__ float mrun[32], lrun[32], scal[32], mka[32];

  const long qbase = ((long)img * kR + b) * kKD;
  const long kbase = KIMG ? ((long)img * kR + b) * kKD : (long)b * kKD;
  const long vbase = (long)(VZ ? z : b) * P8 * kD * 8;

  u32x4 afq[2][4];
#pragma unroll
  for (int mi = 0; mi < 2; ++mi) {
    int qq = qt0 + mi * 16 + fr;
    if (qq >= kHW) qq = kHW - 1;
#pragma unroll
    for (int kk = 0; kk < 4; ++kk)
      afq[mi][kk] = *(const u32x4*)(Q + qbase + (long)qq * (kB * kKD) + kk * 32 + fk * 8);
  }

  f32x4 oacc[2][8] = {};
  if (tid < 32) { mrun[tid] = -3.0e38f; lrun[tid] = 0.f; mka[tid] = 0.f; }
  __syncthreads();

  int r8 = lane >> 3, i8 = lane & 7;
  int srow = wid * 8 + r8;

  // K double-buffer: load tile 0
  u32x4 kcur[4], knxt[4];
  {
    int krow = wid * 16 + fr;
    int kc = krow < S ? krow : S - 1;
    const u16b* kp = K + kbase + (long)kc * (kB * kKD);
#pragma unroll
    for (int kk = 0; kk < 4; ++kk) kcur[kk] = *(const u32x4*)(kp + kk * 32 + fk * 8);
  }

  for (int kt = 0; kt < S; kt += 64) {
    // QK^T strip (uses kcur)
    f32x4 sacc[2] = {};
    __builtin_amdgcn_s_setprio(1);
#pragma unroll
    for (int kk = 0; kk < 4; ++kk) {
      mfma_bf16(sacc[0], afq[0][kk], kcur[kk]);
      mfma_bf16(sacc[1], afq[1][kk], kcur[kk]);
    }
    __builtin_amdgcn_s_setprio(0);
    // prefetch THIS tile's V (panel layout: 256B-contiguous per fk group)
    u32x4 vreg[2][8];
#pragma unroll
    for (int kk = 0; kk < 2; ++kk) {
      int c8 = (kt >> 3) + kk * 4 + fk;
      if (c8 > P8 - 1) c8 = P8 - 1;
      const u16b* vp = V8 + vbase + (long)c8 * kD * 8;
#pragma unroll
      for (int n = 0; n < 8; ++n) {
        int d = wid * 128 + n * 16 + fr;
        vreg[kk][n] = *(const u32x4*)(vp + (long)d * 8);
      }
    }
    // prefetch NEXT tile's K
    const bool more = (kt + 64 < S);
    if (more) {
      int krow2 = kt + 64 + wid * 16 + fr;
      int kc2 = krow2 < S ? krow2 : S - 1;
      const u16b* kp2 = K + kbase + (long)kc2 * (kB * kKD);
#pragma unroll
      for (int kk = 0; kk < 4; ++kk) knxt[kk] = *(const u32x4*)(kp2 + kk * 32 + fk * 8);
    }
    asm volatile("s_nop 7\n\ts_nop 7" ::: );  // MFMA -> VALU hazard
    {
      int krow = kt + wid * 16 + fr;
      if (krow >= S) {
#pragma unroll
        for (int mi = 0; mi < 2; ++mi)
#pragma unroll
          for (int r = 0; r < 4; ++r) sacc[mi][r] = -1.0e30f;
      }
#pragma unroll
      for (int mi = 0; mi < 2; ++mi)
#pragma unroll
        for (int r = 0; r < 4; ++r)
          Ssm[(mi * 16 + fk * 4 + r) * 68 + wid * 16 + fr] = sacc[mi][r];
    }
    ldsbar();  // B1: Ssm RAW (lgkm-only)
    // online softmax
    {
      float v[8];
      float mx = -3.0e38f;
#pragma unroll
      for (int j = 0; j < 8; ++j) {
        v[j] = Ssm[srow * 68 + i8 * 8 + j] * kTemp;
        mx = fmaxf(mx, v[j]);
      }
#pragma unroll
      for (int o = 1; o < 8; o <<= 1) mx = fmaxf(mx, __shfl_xor(mx, o));
      float mold = mrun[srow];
      float mnew = fmaxf(mold, mx);
      float p[8], ts = 0.f, lacc = 0.f;
#pragma unroll
      for (int j = 0; j < 8; ++j) {
        p[j] = __expf(v[j] - mnew);
        ts += p[j];
        if (LAB) {
          int kidx = kt + i8 * 8 + j;
          lacc += p[j] * labv[(long)(kidx < S ? kidx : S - 1) * kB + b];
        }
      }
#pragma unroll
      for (int o = 1; o < 8; o <<= 1) ts += __shfl_xor(ts, o);
      if (LAB) {
#pragma unroll
        for (int o = 1; o < 8; o <<= 1) lacc += __shfl_xor(lacc, o);
      }
      u32x4 w0;
      w0.x = pk2bf(p[0], p[1]); w0.y = pk2bf(p[2], p[3]);
      w0.z = pk2bf(p[4], p[5]); w0.w = pk2bf(p[6], p[7]);
      *(u32x4*)&Plds[srow * 36 + i8 * 4] = w0;
      if (i8 == 0) {
        float sc = __expf(mold - mnew);
        mrun[srow] = mnew;
        lrun[srow] = lrun[srow] * sc + ts;
        scal[srow] = sc;
        if (LAB) mka[srow] = mka[srow] * sc + lacc;
      }
    }
    ldsbar();  // B2: Plds + scal RAW (lgkm-only)
    // rescale O (VALU), then PV (MFMA reads oacc as SrcC)
#pragma unroll
    for (int mi = 0; mi < 2; ++mi)
#pragma unroll
      for (int r = 0; r < 4; ++r) {
        float sc = scal[mi * 16 + fk * 4 + r];
#pragma unroll
        for (int n = 0; n < 8; ++n) oacc[mi][n][r] *= sc;
      }
    asm volatile("s_nop 7" ::: );  // VALU write -> MFMA SrcC read hazard
    __builtin_amdgcn_s_setprio(1);
#pragma unroll
    for (int kk = 0; kk < 2; ++kk) {
      u32x4 ap0 = *(const u32x4*)&Plds[fr * 36 + kk * 16 + fk * 4];
      u32x4 ap1 = *(const u32x4*)&Plds[(16 + fr) * 36 + kk * 16 + fk * 4];
#pragma unroll
      for (int n = 0; n < 8; ++n) {
        mfma_bf16(oacc[0][n], ap0, vreg[kk][n]);
        mfma_bf16(oacc[1][n], ap1, vreg[kk][n]);
      }
    }
    __builtin_amdgcn_s_setprio(0);
    asm volatile("s_nop 7\n\ts_nop 7" ::: );  // MFMA -> VALU
    if (more) {
#pragma unroll
      for (int kk = 0; kk < 4; ++kk) kcur[kk] = knxt[kk];
    }
  }
  asm volatile("s_nop 7\n\ts_nop 7" ::: );
  __syncthreads();  // final full barrier before epilogue
#pragma unroll
  for (int mi = 0; mi < 2; ++mi)
#pragma unroll
    for (int r = 0; r < 4; ++r) {
      int qq = mi * 16 + fk * 4 + r;
      int gq = qt0 + qq;
      if (gq >= kHW) continue;
      float invl = 1.0f / lrun[qq];
      long orow = ((long)img * kR + (long)gq * kB + b) * kD;
#pragma unroll
      for (int n = 0; n < 8; ++n)
        O[orow + wid * 128 + n * 16 + fr] = f2bf(oacc[mi][n][r] * invl);
    }
  if (LAB && tid < 32) {
    int gq = qt0 + tid;
    if (gq < kHW) mkout[(long)img * kR + (long)gq * kB + b] = mka[tid] / lrun[tid];
  }
}

// row += bias; l2-normalize; fp32 in place + bf16 mirror; optional g = u.row
__global__ void k_bias_l2n(float* __restrict__ P, const float* __restrict__ bias, int C,
                           u16b* __restrict__ outb, const float* __restrict__ u,
                           float* __restrict__ g, int L) {
  __shared__ float red[2];
  long row = blockIdx.x;
  float* p = P + row * C;
  int tid = threadIdx.x;  // 128
  int nv = C >> 7;
  float v[4];
  float s = 0.f;
#pragma unroll
  for (int i = 0; i < 4; ++i)
    if (i < nv) {
      float x = p[tid + (i << 7)] + bias[tid + (i << 7)];
      v[i] = x;
      s += x * x;
    }
  s = wsum(s);
  if ((tid & 63) == 0) red[tid >> 6] = s;
  __syncthreads();
  float inv = 1.f / fmaxf(sqrtf(red[0] + red[1]), 1e-12f);
  float dot = 0.f;
#pragma unroll
  for (int i = 0; i < 4; ++i)
    if (i < nv) {
      float x = v[i] * inv;
      p[tid + (i << 7)] = x;
      outb[row * C + tid + (i << 7)] = f2bf(x);
      if (u) dot += x * u[tid + (i << 7)];
    }
  if (u) {
    __syncthreads();
    dot = wsum(dot);
    if ((tid & 63) == 0) red[tid >> 6] = dot;
    __syncthreads();
    if (tid == 0) {
      int img = (int)(row / kR);
      int within = (int)(row % kR);
      int qq = within >> 3, b = within & 7;
      g[((long)(img * 8 + b)) * L + qq] = red[0] + red[1];
    }
  }
}

// generic softmax; optional bf16 out at row*ldo
__global__ __launch_bounds__(256) void k_softmax(float* __restrict__ S, int Lq, int Lk,
                                                 u16b* __restrict__ outb, int ldo) {
  __shared__ float sm[1456];
  __shared__ float red[4];
  int row = blockIdx.x;
  float* Sr = S + (long)row * Lk;
  int tid = threadIdx.x;
  float mx = -3.0e38f;
  for (int k = tid; k < Lk; k += 256) {
    float v = Sr[k] * kTemp;
    sm[k] = v;
    mx = fmaxf(mx, v);
  }
  mx = wmax(mx);
  if ((tid & 63) == 0) red[tid >> 6] = mx;
  __syncthreads();
  mx = fmaxf(fmaxf(red[0], red[1]), fmaxf(red[2], red[3]));
  __syncthreads();
  float s = 0.f;
  for (int k = tid; k < Lk; k += 256) {
    float e = __expf(sm[k] - mx);
    sm[k] = e;
    s += e;
  }
  s = wsum(s);
  if ((tid & 63) == 0) red[tid >> 6] = s;
  __syncthreads();
  float inv = 1.0f / (red[0] + red[1] + red[2] + red[3]);
  for (int k = tid; k < Lk; k += 256) {
    float p = sm[k] * inv;
    if (outb) outb[(long)row * ldo + k] = f2bf(p); else Sr[k] = p;
  }
}

// fused cR + softmax + lab-dot: block z in [0,48)
__global__ __launch_bounds__(256) void k_cwi(const float* __restrict__ vb,
                                             const u16b* __restrict__ Krb,
                                             const float* __restrict__ labv,
                                             float* __restrict__ wI,
                                             float* __restrict__ mki8) {
  __shared__ float sm[kL];
  __shared__ float vbl[kKD];
  __shared__ float red[4];
  int z = blockIdx.x, b = z & 7;
  int tid = threadIdx.x;
  if (tid < kKD) vbl[tid] = vb[(long)z * kKD + tid];
  __syncthreads();
  float mx = -3.0e38f;
  for (int k = tid; k < kL; k += 256) {
    const u16b* kp = Krb + ((long)k * kB + b) * kKD;
    float s = 0.f;
    for (int c = 0; c < kKD; c += 8) {
      u32x4 w = *(const u32x4*)(kp + c);
      s += vbl[c] * bf2f((u16b)(w.x & 0xFFFF)) + vbl[c + 1] * bf2f((u16b)(w.x >> 16));
      s += vbl[c + 2] * bf2f((u16b)(w.y & 0xFFFF)) + vbl[c + 3] * bf2f((u16b)(w.y >> 16));
      s += vbl[c + 4] * bf2f((u16b)(w.z & 0xFFFF)) + vbl[c + 5] * bf2f((u16b)(w.z >> 16));
      s += vbl[c + 6] * bf2f((u16b)(w.w & 0xFFFF)) + vbl[c + 7] * bf2f((u16b)(w.w >> 16));
    }
    sm[k] = s * kTemp;
    mx = fmaxf(mx, sm[k]);
  }
  mx = wmax(mx);
  if ((tid & 63) == 0) red[tid >> 6] = mx;
  __syncthreads();
  mx = fmaxf(fmaxf(red[0], red[1]), fmaxf(red[2], red[3]));
  __syncthreads();
  float s = 0.f;
  for (int k = tid; k < kL; k += 256) {
    float e = __expf(sm[k] - mx);
    sm[k] = e;
    s += e;
  }
  s = wsum(s);
  if ((tid & 63) == 0) red[tid >> 6] = s;
  __syncthreads();
  float inv = 1.0f / (red[0] + red[1] + red[2] + red[3]);
  __syncthreads();
  float dot = 0.f;
  for (int k = tid; k < kL; k += 256) {
    float p = sm[k] * inv;
    wI[(long)z * kL + k] = p;
    dot += p * labv[(long)k * kB + b];
  }
  dot = wsum(dot);
  if ((tid & 63) == 0) red[tid >> 6] = dot;
  __syncthreads();
  if (tid == 0) mki8[z] = red[0] + red[1] + red[2] + red[3];
}

// deterministic rank-1 AV, phase A
__global__ void k_wrowA(const float* __restrict__ g, const float* __restrict__ seq,
                        float* __restrict__ row2) {
  int z = blockIdx.y, img = z >> 3, b = z & 7;
  int c = blockIdx.z;
  int d = blockIdx.x * 128 + threadIdx.x;
  int k0 = c * 61;
  int k1 = min(kHW, k0 + 61);
  float s = 0.f;
  for (int k = k0; k < k1; ++k)
    s += g[(long)z * kHW + k] * seq[((long)img * kR + (long)k * kB + b) * kD + d];
  row2[((long)z * 8 + c) * kD + d] = s;
}

// phase B: row[z*kD+d] = sum_c row2 (fixed order)
__global__ void k_wrowB(const float* __restrict__ row2, float* __restrict__ row) {
  int idx = blockIdx.x * 256 + threadIdx.x;
  int z = idx >> 9, d = idx & 511;
  float s = 0.f;
#pragma unroll
  for (int c = 0; c < 8; ++c) s += row2[((long)z * 8 + c) * kD + d];
  row[(long)z * kD + d] = s;
}

// fp32 inorm phase 1 (encoder)
__global__ __launch_bounds__(256) void k_ss1f(const float* __restrict__ A,
                                              const float* __restrict__ B2,
                                              float* __restrict__ part) {
  __shared__ float red[4];
  long r = blockIdx.x;
  int tid = threadIdx.x;
  long base = r * kD;
  float z0 = A[base + tid] + B2[base + tid];
  float z1 = A[base + tid + 256] + B2[base + tid + 256];
  float s = z0 * z0 + z1 * z1;
  s = wsum(s);
  if ((tid & 63) == 0) red[tid >> 6] = s;
  __syncthreads();
  if (tid == 0) part[r] = red[0] + red[1] + red[2] + red[3];
}

// fp32 inorm phase 3 (encoder): fp32 out + bf16 mirror
__global__ __launch_bounds__(256) void k_scale1f(const float* __restrict__ A,
                                                 const float* __restrict__ B2,
                                                 float* __restrict__ outp,
                                                 const float* __restrict__ ss,
                                                 u16b* __restrict__ ob) {
  long r = blockIdx.x;
  int l = (int)(r / kB), b = (int)(r % kB);
  int g = (l / kHW) * kB + b;
  int tid = threadIdx.x;
  float fac = kScaleN * sqrtf(kCnt / (ss[g] + 1e-5f));
  long base = r * kD;
  float x0 = (A[base + tid] + B2[base + tid]) * fac;
  float x1 = (A[base + tid + 256] + B2[base + tid + 256]) * fac;
  outp[base + tid] = x0;
  outp[base + tid + 256] = x1;
  ob[base + tid] = f2bf(x0);
  ob[base + tid + 256] = f2bf(x1);
}

// t1 inorm, phase 1 (B2 bf16)
__global__ __launch_bounds__(256) void k_ss1b(const float* __restrict__ A,
                                              const u16b* __restrict__ B2,
                                              float* __restrict__ part) {
  __shared__ float red[4];
  long r = blockIdx.x;
  int tid = threadIdx.x;
  long base = r * kD;
  float z0 = A[base + tid] + bf2f(B2[base + tid]);
  float z1 = A[base + tid + 256] + bf2f(B2[base + tid + 256]);
  float s = z0 * z0 + z1 * z1;
  s = wsum(s);
  if ((tid & 63) == 0) red[tid >> 6] = s;
  __syncthreads();
  if (tid == 0) part[r] = red[0] + red[1] + red[2] + red[3];
}

__global__ void k_ssred(const float* __restrict__ part, float* __restrict__ ss, int R, int NG) {
  __shared__ float red[8];
  int g = blockIdx.x, v = blockIdx.y;
  int n = g / kB, b = g % kB;
  int tid = threadIdx.x;  // 512
  float s = 0.f;
  for (int p = tid; p < kHW; p += 512) s += part[(long)v * R + ((long)(n * kHW + p) * kB + b)];
  s = wsum(s);
  if ((tid & 63) == 0) red[tid >> 6] = s;
  __syncthreads();
  if (tid == 0) {
    float t = 0.f;
#pragma unroll
    for (int i = 0; i < 8; ++i) t += red[i];
    ss[(long)v * NG + g] = t;
  }
}

// t1 inorm, phase 3 -> bf16 only
__global__ __launch_bounds__(256) void k_scale1b(const float* __restrict__ A,
                                                 const u16b* __restrict__ B2,
                                                 const float* __restrict__ ss,
                                                 u16b* __restrict__ ob) {
  long r = blockIdx.x;
  int img = (int)(r / kR), b = (int)(r & 7);
  int g = img * 8 + b;
  int tid = threadIdx.x;
  float fac = kScaleN * sqrtf(kCnt / (ss[g] + 1e-5f));
  long base = r * kD;
  ob[base + tid] = f2bf((A[base + tid] + bf2f(B2[base + tid])) * fac);
  ob[base + tid + 256] = f2bf((A[base + tid + 256] + bf2f(B2[base + tid + 256])) * fac);
}

// ti8[z,d] = row[z,d] * scale(kHW * ||row||^2)
__global__ void k_ti8(const float* __restrict__ row, float* __restrict__ ti8) {
  __shared__ float red[4];
  int z = blockIdx.x;
  int tid = threadIdx.x;  // 256
  float r0 = row[(long)z * kD + tid], r1 = row[(long)z * kD + tid + 256];
  float s = r0 * r0 + r1 * r1;
  s = wsum(s);
  if ((tid & 63) == 0) red[tid >> 6] = s;
  __syncthreads();
  float ssv = (float)kHW * (red[0] + red[1] + red[2] + red[3]);
  float fac = kScaleN * sqrtf(kCnt / (ssv + 1e-5f));
  ti8[(long)z * kD + tid] = r0 * fac;
  ti8[(long)z * kD + tid + 256] = r1 * fac;
}

// vb[z,:] = l2n(ti8_z @ WkC + bkC)
__global__ void k_vb(const float* __restrict__ ti8, const float* __restrict__ Wk,
                     const float* __restrict__ bk, float* __restrict__ vb) {
  __shared__ float part[4][128];
  __shared__ float red[2];
  int z = blockIdx.x;
  int j = threadIdx.x;
  int dz = threadIdx.y;
  const float* row = ti8 + (long)z * kD;
  float acc = 0.f;
  int d0 = dz * 128;
  for (int d = d0; d < d0 + 128; ++d) acc += row[d] * Wk[(long)d * kKD + j];
  part[dz][j] = acc;
  __syncthreads();
  if (dz == 0) {
    float a = part[0][j] + part[1][j] + part[2][j] + part[3][j] + bk[j];
    float s = a * a;
    s = wsum(s);
    if ((j & 63) == 0) red[j >> 6] = s;
    part[0][j] = a;
  }
  __syncthreads();
  if (dz == 0) {
    float inv = 1.f / fmaxf(sqrtf(red[0] + red[1]), 1e-12f);
    vb[(long)z * kKD + j] = part[0][j] * inv;
  }
}

// ci8[z,d] = sum_l wI[z,l] * VrT[b][d][l]
__global__ void k_ci8(const float* __restrict__ wI, const u16b* __restrict__ VrT,
                      float* __restrict__ ci8) {
  int idx = blockIdx.x * 4 + (threadIdx.x >> 6);
  int z = idx >> 9, d = idx & 511;
  int b = z & 7;
  int lane = threadIdx.x & 63;
  const float* w = wI + (long)z * kL;
  const u16b* vt = VrT + ((long)b * kD + d) * kLp;
  float s = 0.f;
  for (int l = lane; l < kL; l += 64) s += w[l] * bf2f(vt[l]);
  s = wsum(s);
  if (lane == 0) ci8[(long)z * kD + d] = s;
}

// tail partials: v in {a^2, b^2, ab}, a = t1*mk, b = t1 + c3 (bf16 inputs)
__global__ __launch_bounds__(256) void k_ss3b(const u16b* __restrict__ t1b,
                                              const float* __restrict__ mkr,
                                              const u16b* __restrict__ c3b,
                                              float* __restrict__ part) {
  __shared__ float red[4][3];
  long r = blockIdx.x;
  int tid = threadIdx.x;
  long base = r * kD;
  float mk = mkr[r];
  float s0 = 0.f, s1 = 0.f, s2 = 0.f;
#pragma unroll
  for (int j = 0; j < 2; ++j) {
    int d = tid + j * 256;
    float t = bf2f(t1b[base + d]);
    float a = t * mk;
    float bb = t + bf2f(c3b[base + d]);
    s0 += a * a; s1 += bb * bb; s2 += a * bb;
  }
  int w = tid >> 6, lane = tid & 63;
  float t0 = wsum(s0), t1 = wsum(s1), t2 = wsum(s2);
  if (lane == 0) { red[w][0] = t0; red[w][1] = t1; red[w][2] = t2; }
  __syncthreads();
  if (tid < 3)
    part[(long)tid * kR6 + r] = red[0][tid] + red[1][tid] + red[2][tid] + red[3][tid];
}

// per-image coefficients + oi8 (imag analytic)
__global__ __launch_bounds__(512) void k_coef(const float* __restrict__ ssp,
                                              const float* __restrict__ ti8,
                                              const float* __restrict__ ci8,
                                              const float* __restrict__ mki8,
                                              float* __restrict__ coef,
                                              float* __restrict__ oi8) {
  __shared__ float cai[8], cbi[8];
  int img = blockIdx.x;
  int tid = threadIdx.x;
  int b = tid >> 6, lane = tid & 63;
  int z = img * 8 + b;
  float sT = 0.f, sU = 0.f, sV = 0.f;
  for (int d = lane; d < kD; d += 64) {
    float ti = ti8[(long)z * kD + d], ci = ci8[(long)z * kD + d];
    float u = ti + ci;
    sT += ti * ti; sU += u * u; sV += ti * u;
  }
  sT = wsum(sT); sU = wsum(sU); sV = wsum(sV);
  if (lane == 0) {
    float SSa = ssp[z], SSb = ssp[48 + z], SSab = ssp[96 + z];
    float f2 = kScaleN * sqrtf(kCnt / (SSa + 1e-5f));
    float f4 = kScaleN * sqrtf(kCnt / (SSb + 1e-5f));
    float ssz = f2 * f2 * SSa + f4 * f4 * SSb + 2.f * f2 * f4 * SSab;
    float fac = kScaleN * sqrtf(kCnt / (ssz + 1e-5f));
    coef[img * 16 + b] = f2 * fac;
    coef[img * 16 + 8 + b] = f4 * fac;
    float mk = mki8[z];
    float SSai = (float)kHW * mk * mk * sT;
    float SSbi = (float)kHW * sU;
    float SSabi = (float)kHW * mk * sV;
    float f2i = kScaleN * sqrtf(kCnt / (SSai + 1e-5f));
    float f4i = kScaleN * sqrtf(kCnt / (SSbi + 1e-5f));
    float sszi = f2i * f2i * SSai + f4i * f4i * SSbi + 2.f * f2i * f4i * SSabi;
    float faci = kScaleN * sqrtf(kCnt / (sszi + 1e-5f));
    cai[b] = f2i * faci;
    cbi[b] = f4i * faci;
  }
  __syncthreads();
#pragma unroll
  for (int j = 0; j < 8; ++j) {
    int i = tid * 8 + j;
    int bb = i >> 9, d = i & 511;
    int zz = img * 8 + bb;
    float ti = ti8[(long)zz * kD + d], ci = ci8[(long)zz * kD + d];
    oi8[(long)img * 4096 + i] = ti * mki8[zz] * cai[bb] + (ti + ci) * cbi[bb];
  }
}

// oadd[img][o*8+b] = Wc_imag_row(o) . oi8[img*8+b]
__global__ void k_oadd(const float* __restrict__ Wc, const float* __restrict__ oi8,
                       float* __restrict__ oadd) {
  int idx = blockIdx.x * 4 + (threadIdx.x >> 6);
  int img = idx >> 12, rem = idx & 4095;
  int o = rem >> 3, b = rem & 7;
  int lane = threadIdx.x & 63;
  const float* wrow = Wc + (long)o * 1024 + 512;
  const float* oi = oi8 + (long)img * 4096 + (long)b * kD;
  float s = 0.f;
  for (int d = lane; d < kD; d += 64) s += wrow[d] * oi[d];
  s = wsum(s);
  if (lane == 0) oadd[(long)img * 4096 + o * 8 + b] = s;
}

// t2b[r][d] = bf16( t1*mk*ca + (t1+c3)*cb )
__global__ __launch_bounds__(256) void k_zfinb(const u16b* __restrict__ t1b,
                                               const float* __restrict__ mkr,
                                               const u16b* __restrict__ c3b,
                                               const float* __restrict__ coef,
                                               u16b* __restrict__ t2b) {
  long r = blockIdx.x;
  int img = (int)(r / kR), b = (int)(r & 7);
  int tid = threadIdx.x;
  float mk = mkr[r];
  float ca = coef[img * 16 + b], cb = coef[img * 16 + 8 + b];
  long base = r * kD;
#pragma unroll
  for (int j = 0; j < 2; ++j) {
    int d = tid + j * 256;
    float t = bf2f(t1b[base + d]);
    float ov = t * mk * ca + (t + bf2f(c3b[base + d])) * cb;
    t2b[base + d] = f2bf(ov);
  }
}

template <int BM, int BN, bool AF32, bool ACC>
void gemm(hipStream_t s, const void* A, const u16b* B, float* C, int M, int N, int K, int lda,
          int ldb, int ldc, long sA1, long sA2, long sB1, long sB2, long sC1, long sC2,
          int batch, const float* addv = nullptr) {
  dim3 grd(CDIV(N, BN), CDIV(M, BM), batch), blk(256);
  k_gemm<BM, BN, AF32, ACC><<<grd, blk, 0, s>>>(A, B, C, M, N, K, lda, ldb, ldc, sA1, sA2,
                                                sB1, sB2, sC1, sC2, addv);
}

}  // namespace

extern "C" void kernel_launch(void* const* d_in, const int* in_sizes, int n_in, void* d_out,
                              int out_size, void* d_ws, size_t ws_size, hipStream_t stream) {
  (void)in_sizes; (void)n_in; (void)out_size;
  const float* tf  = (const float*)d_in[0];
  const float* sf  = (const float*)d_in[1];
  const float* tl  = (const float*)d_in[2];
  const float* WkE = (const float*)d_in[3];
  const float* bkE = (const float*)d_in[4];
  const float* WkS = (const float*)d_in[5];
  const float* bkS = (const float*)d_in[6];
  const float* WkC = (const float*)d_in[7];
  const float* bkC = (const float*)d_in[8];
  const float* Wc  = (const float*)d_in[9];
  float* out = (float*)d_out;
  float* ws = (float*)d_ws;

  const long LBD = (long)kL * kB * kD;
  const long LBK = (long)kL * kB * kKD;

  long off = 0;
  auto alloc = [&](long n) { long o = off; off += (n + 255) & ~255L; return o; };
  auto allocU = [&](long nu) { return alloc((nu + 1) / 2); };

  long o_seqT = alloc(LBD);
  long o_seqS = alloc(LBD);
  long o_Kr   = alloc(LBK);
  long o_Krb  = allocU(LBK);
  long o_VrT  = allocU((long)kB * kD * kLp);
  long o_tfb  = allocU((long)kNI * kB * kD * kHWp);
  long o_sfb  = allocU((long)kNI * kB * kD * kHWp);
  long o_WkTE = allocU((long)kD * kD);
  long o_WkTS = allocU((long)kKD * kD);
  long o_WkTC = allocU((long)kKD * kD);
  long o_Wcb  = allocU((long)kD * 2 * kD);
  long o_lab  = alloc((long)kL * kB);
  long o_uS   = alloc(kKD);
  long o_vb   = alloc(48L * kKD);
  long o_g    = alloc(48L * kHW);
  long o_wI   = alloc(48L * kL);
  long o_row  = alloc(48L * kD);
  long o_row2 = alloc(48L * 8 * kD);
  long o_mkr  = alloc((long)kR6);
  long o_mki8 = alloc(48);
  long o_ti8  = alloc(48L * kD);
  long o_ci8  = alloc(48L * kD);
  long o_oi8  = alloc(48L * kD);
  long o_oadd = alloc(6L * kD * 8);
  long o_ss   = alloc(512);
  long o_part = alloc(3L * kR6);
  long o_scr  = off;

  // encoder overlay
  long o_Pe  = o_scr;
  long o_Peb = o_Pe + LBD;
  long o_Ae  = o_Peb + LBD / 2;
  long o_Aeb = o_Ae + (long)kB * kL * kL;
  long enc_end = o_Aeb + (8L * kL * kLp + 1) / 2;
  long o_ar  = o_Pe;   // after Pe dead
  long o_mr  = o_Ae;   // after Ae dead

  // decoder overlay (batched over 6 images)
  long p = o_scr;
  auto nxt = [&](long n) { long o = p; p += (n + 255) & ~255L; return o; };
  long o_Ps   = nxt((long)kR6 * kKD);
  long o_Psb  = nxt(((long)kR6 * kKD + 1) / 2);
  long o_Pcb  = nxt(((long)kR6 * kKD + 1) / 2);
  long o_s2rb = nxt(((long)kR6 * kD + 1) / 2);
  long o_t1rb = nxt(((long)kR6 * kD + 1) / 2);
  long o_c3rb = nxt(((long)kR6 * kD + 1) / 2);
  long o_t2b  = nxt(((long)kR6 * kD + 1) / 2);
  long o_V8s  = nxt((48L * kP8s * kD * 8 + 1) / 2);
  long o_V8c  = nxt((8L * kP8c * kD * 8 + 1) / 2);
  long img_end = p;

  long total = (enc_end > img_end ? enc_end : img_end);
  if ((size_t)total * sizeof(float) > ws_size) return;

  float* seqT = ws + o_seqT;
  float* Kr = ws + o_Kr;
  u16b* Krb = (u16b*)(ws + o_Krb);
  u16b* VrT = (u16b*)(ws + o_VrT);
  u16b* tfb = (u16b*)(ws + o_tfb);
  float* lab = ws + o_lab;
  float* uS = ws + o_uS;
  float* vb = ws + o_vb;
  float* g_ = ws + o_g;
  float* wI = ws + o_wI;
  float* row = ws + o_row;
  float* row2 = ws + o_row2;
  float* mkr = ws + o_mkr;
  float* mki8 = ws + o_mki8;
  float* ti8 = ws + o_ti8;
  float* ci8 = ws + o_ci8;
  float* oi8 = ws + o_oi8;
  float* oadd = ws + o_oadd;
  float* ssp = ws + o_ss;
  float* coef = ssp + 160;
  float* part = ws + o_part;
  float* Pe = ws + o_Pe;
  u16b* Peb = (u16b*)(ws + o_Peb);
  float* Ae = ws + o_Ae;
  u16b* Aeb = (u16b*)(ws + o_Aeb);
  float* ar = ws + o_ar;
  float* mr = ws + o_mr;
  u16b* mrb = (u16b*)(ws + o_mr + LBD);
  float* Ps = ws + o_Ps;
  u16b* Psb = (u16b*)(ws + o_Psb);
  u16b* Pcb = (u16b*)(ws + o_Pcb);
  u16b* s2rb = (u16b*)(ws + o_s2rb);
  u16b* t1rb = (u16b*)(ws + o_t1rb);
  u16b* c3rb = (u16b*)(ws + o_c3rb);
  u16b* t2b = (u16b*)(ws + o_t2b);
  u16b* V8s = (u16b*)(ws + o_V8s);
  u16b* V8c = (u16b*)(ws + o_V8c);
  u16b* WkTE = (u16b*)(ws + o_WkTE);
  u16b* WkTS = (u16b*)(ws + o_WkTS);
  u16b* WkTC = (u16b*)(ws + o_WkTC);
  u16b* Wcb = (u16b*)(ws + o_Wcb);

  // ---- stage 0 ----
  {
    dim3 grd(CDIV(kHW, 32), CDIV(kD, 32), kNI * kB), blk(32, 8);
    k_toseq<<<grd, blk, 0, stream>>>(tf, seqT);
    k_toseq<<<grd, blk, 0, stream>>>(sf, ws + o_seqS);
  }
  k_cvt2d<<<kNI * kB * kD, 256, 0, stream>>>(tf, tfb, kHW, kHWp);
  k_cvt2d<<<kNI * kB * kD, 256, 0, stream>>>(sf, (u16b*)(ws + o_sfb), kHW, kHWp);
  k_cvt2d<<<kD, 256, 0, stream>>>(Wc, Wcb, 2 * kD, 2 * kD);
  k_tcvt<<<dim3(kD / 32, kD / 32), dim3(32, 8), 0, stream>>>(WkE, WkTE, kD, kD);
  k_tcvt<<<dim3(kKD / 32, kD / 32), dim3(32, 8), 0, stream>>>(WkS, WkTS, kD, kKD);
  k_tcvt<<<dim3(kKD / 32, kD / 32), dim3(32, 8), 0, stream>>>(WkC, WkTC, kD, kKD);
  k_lab<<<CDIV(kNI * kB * kHW, 256), 256, 0, stream>>>(tl, lab);
  k_l2n_vec<<<1, 128, 0, stream>>>(bkS, uS, kKD);

  // ---- encoder (imag branch dead) ----
  gemm<64, 128, true, false>(stream, seqT, WkTE, Pe, kL * kB, kD, kD, kD, kD, kD,
                             0, 0, 0, 0, 0, 0, 1);
  k_bias_l2n<<<kL * kB, 128, 0, stream>>>(Pe, bkE, kD, Peb, nullptr, nullptr, 0);
  gemm<128, 128, false, false>(stream, Peb, Peb, Ae, kL, kL, kD, kB * kD, kB * kD, kL,
                               0, kD, 0, kD, 0, (long)kL * kL, 8);
  k_softmax<<<kB * kL, 256, 0, stream>>>(Ae, kL, kL, Aeb, kLp);
  gemm<64, 128, false, false>(stream, Aeb, tfb, ar, kL, kD, kHW, kLp, kHWp, kB * kD,
                              0, (long)kL * kLp, 0, (long)kD * kHWp, 0, kD, 8);
  gemm<64, 128, false, true>(stream, Aeb + kHW, tfb + (long)kB * kD * kHWp, ar, kL, kD, kHW,
                             kLp, kHWp, kB * kD, 0, (long)kL * kLp, 0, (long)kD * kHWp, 0, kD,
                             8);
  gemm<64, 128, false, true>(stream, Aeb + 2 * kHW, tfb + 2L * kB * kD * kHWp, ar, kL, kD,
                             kHW, kLp, kHWp, kB * kD, 0, (long)kL * kLp, 0, (long)kD * kHWp,
                             0, kD, 8);
  // mem_r = inorm(seqT + ar)
  k_ss1f<<<kL * kB, 256, 0, stream>>>(seqT, ar, part);
  k_ssred<<<dim3(kNI * kB, 1), 512, 0, stream>>>(part, ssp, kL * kB, kNI * kB);
  k_scale1f<<<kL * kB, 256, 0, stream>>>(seqT, ar, mr, ssp, mrb);
  k_vrt<<<dim3(CDIV(kL, 32), kD / 32, kB), dim3(32, 8), 0, stream>>>(mr, lab, VrT);
  gemm<64, 64, false, false>(stream, mrb, WkTC, Kr, kL * kB, kKD, kD, kD, kD, kKD,
                             0, 0, 0, 0, 0, 0, 1);
  k_bias_l2n<<<kL * kB, 128, 0, stream>>>(Kr, bkC, kKD, Krb, nullptr, nullptr, 0);

  // ---- decoder (fully batched over 48 = 6 img x 8 b) ----
  // V panel repacks (decoder overlay region; encoder overlay now dead)
  k_vpack<<<48 * kP8s * kD * 8 / 256, 256, 0, stream>>>(tfb, V8s, kHWp, kP8s, kHW);
  k_vpack<<<8 * kP8c * kD * 8 / 256, 256, 0, stream>>>(VrT, V8c, kLp, kP8c, kL);
  gemm<64, 128, true, false>(stream, seqT, WkTS, Ps, kR6, kKD, kD, kD, kD, kKD,
                             0, 0, 0, 0, 0, 0, 1);
  k_bias_l2n<<<kR6, 128, 0, stream>>>(Ps, bkS, kKD, Psb, uS, g_, kHW);
  k_softmax<<<48, 256, 0, stream>>>(g_, 1, kHW, nullptr, 0);  // wi rows
  k_wrowA<<<dim3(kD / 128, 48, 8), 128, 0, stream>>>(g_, seqT, row2);
  k_wrowB<<<48 * kD / 256, 256, 0, stream>>>(row2, row);
  k_ti8<<<48, 256, 0, stream>>>(row, ti8);
  k_vb<<<48, dim3(128, 4), 0, stream>>>(ti8, WkC, bkC, vb);
  // self-attention flash: s2r (V8s, panels)
  k_flash<false, true, true><<<768, 256, 0, stream>>>(Psb, Psb, V8s, nullptr, s2rb,
                                                      nullptr, kHW, kP8s);
  // t1r = inorm(t + s2r) -> bf16
  k_ss1b<<<kR6, 256, 0, stream>>>(seqT, s2rb, part);
  k_ssred<<<dim3(48, 1), 512, 0, stream>>>(part, ssp, kR6, 48);
  k_scale1b<<<kR6, 256, 0, stream>>>(seqT, s2rb, ssp, t1rb);
  // cross projection
  gemm<64, 128, false, false>(stream, t1rb, WkTC, Ps, kR6, kKD, kD, kD, kD, kKD,
                              0, 0, 0, 0, 0, 0, 1);
  k_bias_l2n<<<kR6, 128, 0, stream>>>(Ps, bkC, kKD, Pcb, nullptr, nullptr, 0);
  // imag branch (q-independent)
  k_cwi<<<48, 256, 0, stream>>>(vb, Krb, lab, wI, mki8);
  k_ci8<<<48 * 512 / 4, 256, 0, stream>>>(wI, VrT, ci8);
  // cross flash: c3r + mkr (V8c, panels)
  k_flash<true, false, false><<<768, 256, 0, stream>>>(Pcb, Krb, V8c, lab, c3rb,
                                                       mkr, kL, kP8c);
  // fused tail
  k_ss3b<<<kR6, 256, 0, stream>>>(t1rb, mkr, c3rb, part);
  k_ssred<<<dim3(48, 3), 512, 0, stream>>>(part, ssp, kR6, 48);
  k_coef<<<6, 512, 0, stream>>>(ssp, ti8, ci8, mki8, coef, oi8);
  k_oadd<<<6 * 4096 / 4, 256, 0, stream>>>(Wc, oi8, oadd);
  k_zfinb<<<kR6, 256, 0, stream>>>(t1rb, mkr, c3rb, coef, t2b);
  // 1x1 conv: batch 48, K=512 real + rank-1 imag epilogue
  gemm<64, 64, false, false>(stream, Wcb, t2b, out, kD, kHW, kD, 2 * kD, kB * kD, kHW,
                             0, 0, (long)kR * kD, kD, 8L * kD * kHW, (long)kD * kHW, 48, oadd);
}

// Round 19
// 769.217 us; speedup vs baseline: 1.0530x; 1.0032x over previous
//
#include <hip/hip_runtime.h>

// ComTransformer on MI355X — round 19: K panel-repack (same mechanism as round
// 18's V repack, which cut flash 187->135us).
//  - K packed to K8p[z][k16][cseg][16][8]: QK^T loads become 256B-contiguous per
//    fk group (~4 requests/instr vs 16). Pad rows zero-filled (masked post-MFMA).
// Prior: V panels, lgkm-only flash barriers, XCD-local flash grid, batched
// decoder, rank-1 imag collapse, pipelined BK=64 bf16 NT GEMM + XCD swizzle.

namespace {

constexpr int kNI = 3;
constexpr int kB  = 8;
constexpr int kD  = 512;
constexpr int kKD = 128;
constexpr int kHW = 484;
constexpr int kL  = kNI * kHW;  // 1452
constexpr int kLp = 1456;
constexpr int kHWp = 488;
constexpr float kTemp = 30.0f;
constexpr float kCnt  = 247808.0f;
constexpr float kScaleN = 0.011048543456039806f;
constexpr int kR = kHW * kB;   // 3872 rows per image
constexpr int kR6 = 6 * kR;    // 23232
constexpr int kP8s = kHWp / 8;   // 61 panels (self V)
constexpr int kP8c = kLp / 8;    // 182 panels (cross V)
constexpr int kP16s = 31;        // 16-row K panels, self (496 rows padded)
constexpr int kP16c = kLp / 16;  // 91 panels, cross

#define CDIV(a, b) (((a) + (b) - 1) / (b))

typedef float f32x4 __attribute__((ext_vector_type(4)));
typedef unsigned int u32x4 __attribute__((ext_vector_type(4)));
typedef unsigned short u16b;

__device__ __forceinline__ float wsum(float v) {
#pragma unroll
  for (int o = 32; o; o >>= 1) v += __shfl_down(v, o);
  return v;
}
__device__ __forceinline__ float wmax(float v) {
#pragma unroll
  for (int o = 32; o; o >>= 1) v = fmaxf(v, __shfl_down(v, o));
  return v;
}

__device__ __forceinline__ unsigned pk2bf(float lo, float hi) {
  union { float f; unsigned u; } a, b;
  a.f = lo; b.f = hi;
  unsigned ra = (a.u + 0x7FFFu + ((a.u >> 16) & 1u)) >> 16;
  unsigned rb = (b.u + 0x7FFFu + ((b.u >> 16) & 1u)) >> 16;
  return (ra & 0xFFFFu) | (rb << 16);
}
__device__ __forceinline__ u16b f2bf(float x) {
  union { float f; unsigned u; } a;
  a.f = x;
  return (u16b)((a.u + 0x7FFFu + ((a.u >> 16) & 1u)) >> 16);
}
__device__ __forceinline__ float bf2f(u16b x) {
  union { unsigned u; float f; } a;
  a.u = (unsigned)x << 16;
  return a.f;
}

__device__ __forceinline__ void mfma_bf16(f32x4& d, const u32x4& a, const u32x4& b) {
  asm("v_mfma_f32_16x16x32_bf16 %0, %1, %2, %0" : "+v"(d) : "v"(a), "v"(b));
}

// LDS-only barrier (global loads stay in flight across it)
__device__ __forceinline__ void ldsbar() {
  asm volatile("s_waitcnt lgkmcnt(0)" ::: "memory");
  __builtin_amdgcn_s_barrier();
  asm volatile("" ::: "memory");
}

// ---------------- layout transform: [n,b,d,hw] -> seq [(n*hw),b,d] fp32 -----------
__global__ void k_toseq(const float* __restrict__ in, float* __restrict__ out) {
  __shared__ float tile[32][33];
  int nb = blockIdx.z;
  int n = nb / kB, b = nb % kB;
  int p0 = blockIdx.x * 32, d0 = blockIdx.y * 32;
  int tx = threadIdx.x, ty = threadIdx.y;
#pragma unroll
  for (int j = 0; j < 4; ++j) {
    int d = d0 + ty + j * 8, p = p0 + tx;
    if (d < kD && p < kHW) tile[ty + j * 8][tx] = in[(long)nb * kD * kHW + (long)d * kHW + p];
  }
  __syncthreads();
#pragma unroll
  for (int j = 0; j < 4; ++j) {
    int p = p0 + ty + j * 8, d = d0 + tx;
    if (p < kHW && d < kD)
      out[((long)(n * kHW + p) * kB + b) * kD + d] = tile[tx][ty + j * 8];
  }
}

__global__ void k_cvt2d(const float* __restrict__ in, u16b* __restrict__ out, int C, int Cp) {
  long r = blockIdx.x;
  for (int c = threadIdx.x; c < C; c += 256)
    out[r * Cp + c] = f2bf(in[r * (long)C + c]);
}

__global__ void k_tcvt(const float* __restrict__ in, u16b* __restrict__ out, int R, int C) {
  __shared__ float tile[32][33];
  int c0 = blockIdx.x * 32, r0 = blockIdx.y * 32;
  int tx = threadIdx.x, ty = threadIdx.y;
#pragma unroll
  for (int j = 0; j < 4; ++j) {
    int r = r0 + ty + j * 8, c = c0 + tx;
    if (r < R && c < C) tile[ty + j * 8][tx] = in[(long)r * C + c];
  }
  __syncthreads();
#pragma unroll
  for (int j = 0; j < 4; ++j) {
    int c = c0 + ty + j * 8, r = r0 + tx;
    if (r < R && c < C) out[(long)c * R + r] = f2bf(tile[tx][ty + j * 8]);
  }
}

// VrT[b][d][l] = bf16( mr[(l,b),d] * lab[l,b] ), stride kLp
__global__ void k_vrt(const float* __restrict__ mr, const float* __restrict__ lab,
                      u16b* __restrict__ vt) {
  __shared__ float tile[32][33];
  int l0 = blockIdx.x * 32, d0 = blockIdx.y * 32, b = blockIdx.z;
  int tx = threadIdx.x, ty = threadIdx.y;
#pragma unroll
  for (int j = 0; j < 4; ++j) {
    int l = l0 + ty + j * 8;
    if (l < kL)
      tile[ty + j * 8][tx] = mr[((long)l * kB + b) * kD + d0 + tx] * lab[(long)l * kB + b];
  }
  __syncthreads();
#pragma unroll
  for (int j = 0; j < 4; ++j) {
    int d = d0 + ty + j * 8, l = l0 + tx;
    if (l < kL) vt[((long)b * kD + d) * kLp + l] = f2bf(tile[tx][ty + j * 8]);
  }
}

// pack V [Z][kD][ldv] -> V8 [Z][P][kD][8]; pad cols zero-filled
__global__ void k_vpack(const u16b* __restrict__ in, u16b* __restrict__ out,
                        int ldv, int P, int Sreal) {
  long idx = (long)blockIdx.x * 256 + threadIdx.x;
  int j = (int)(idx & 7);
  int d = (int)((idx >> 3) & 511);
  long t = idx >> 12;
  int c8 = (int)(t % P);
  int z = (int)(t / P);
  int col = c8 * 8 + j;
  u16b v = (col < Sreal) ? in[((long)z * kD + d) * ldv + col] : (u16b)0;
  out[idx] = v;
}

// pack K rows (imgIdx*imgStride + k*8 + b)*kKD -> K8p[z][k16][cseg16][lane16][8]
__global__ void k_kpack(const u16b* __restrict__ in, u16b* __restrict__ out,
                        int P16, int Sreal, long imgStride) {
  long idx = (long)blockIdx.x * 256 + threadIdx.x;
  int j = (int)(idx & 7);
  int l = (int)((idx >> 3) & 15);
  int cseg = (int)((idx >> 7) & 15);
  long t = idx >> 11;
  int k16 = (int)(t % P16);
  int z = (int)(t / P16);
  int b = z & 7, img = z >> 3;
  int k = k16 * 16 + l;
  int c = cseg * 8 + j;
  u16b v = (k < Sreal) ? in[((long)img * imgStride + (long)k * kB + b) * kKD + c] : (u16b)0;
  out[idx] = v;
}

__global__ void k_lab(const float* __restrict__ tl, float* __restrict__ lab) {
  long i = (long)blockIdx.x * 256 + threadIdx.x;
  const long tot = (long)kNI * kB * kHW;
  if (i >= tot) return;
  int p = (int)(i % kHW);
  long t = i / kHW;
  int b = (int)(t % kB);
  int n = (int)(t / kB);
  lab[(long)(n * kHW + p) * kB + b] = tl[i];
}

__global__ void k_l2n_vec(const float* __restrict__ src, float* __restrict__ u, int C) {
  __shared__ float red[2];
  int tid = threadIdx.x;  // 128
  float s = 0.f;
  for (int c = tid; c < C; c += 128) { float x = src[c]; s += x * x; }
  s = wsum(s);
  if ((tid & 63) == 0) red[tid >> 6] = s;
  __syncthreads();
  float inv = 1.f / fmaxf(sqrtf(red[0] + red[1]), 1e-12f);
  for (int c = tid; c < C; c += 128) u[c] = src[c] * inv;
}

// ---------------- pipelined NT bf16 MFMA GEMM (XCD swizzle, 2-stride batch) -------
template <int BM, int BN, bool AF32, bool ACC>
__global__ __launch_bounds__(256) void k_gemm(const void* Ap, const u16b* __restrict__ B,
                                              float* __restrict__ C, int M, int N, int K,
                                              int lda, int ldb, int ldc,
                                              long sA1, long sA2, long sB1, long sB2,
                                              long sC1, long sC2,
                                              const float* __restrict__ addv) {
  const int gx = gridDim.x, gy = gridDim.y;
  const int nwg = gx * gy * gridDim.z;
  const int orig = (blockIdx.z * gy + blockIdx.y) * gx + blockIdx.x;
  const int q = nwg >> 3, rr = nwg & 7, xcd = orig & 7, idx = orig >> 3;
  const int swz = (xcd < rr ? xcd * (q + 1) : rr * (q + 1) + (xcd - rr) * q) + idx;
  const int bx = swz % gx;
  const int tmp = swz / gx;
  const int by = tmp % gy, bz = tmp / gy;
  const int za = bz >> 3, zb = bz & 7;

  const char* Ab = (const char*)Ap + (za * sA1 + zb * sA2) * (AF32 ? 4 : 2);
  const u16b* Bb = B + za * sB1 + zb * sB2;
  C += za * sC1 + zb * sC2;
  constexpr int FM = BM / 32, FN = BN / 32;
  constexpr int NSA = BM * 8 / 256;
  constexpr int NSB = BN * 8 / 256;
  const int m0 = by * BM, n0 = bx * BN;
  const int tid = threadIdx.x;
  const int wid = tid >> 6, lane = tid & 63;
  const int wr = wid >> 1, wc = wid & 1;
  const int fr = lane & 15, fk = lane >> 4;

  __shared__ unsigned AsU[BM * 36];
  __shared__ unsigned BsU[BN * 36];
  f32x4 acc[FM][FN] = {};

  u32x4 pa[NSA];
  float4 paf[AF32 ? 2 * NSA : 1];
  u32x4 pb[NSB];

  auto loadA = [&](int k0) {
#pragma unroll
    for (int i = 0; i < NSA; ++i) {
      int si = tid + i * 256;
      int row = si >> 3, c = si & 7;
      int gr = m0 + row, gk = k0 + c * 8;
      if constexpr (AF32) {
        const float* A = (const float*)Ab;
        if (gr < M && gk + 8 <= K) {
          const float* ap = A + (long)gr * lda + gk;
          paf[2 * i] = *(const float4*)ap;
          paf[2 * i + 1] = *(const float4*)(ap + 4);
        } else {
          float v[8];
#pragma unroll
          for (int j = 0; j < 8; ++j)
            v[j] = (gr < M && gk + j < K) ? A[(long)gr * lda + gk + j] : 0.f;
          paf[2 * i] = make_float4(v[0], v[1], v[2], v[3]);
          paf[2 * i + 1] = make_float4(v[4], v[5], v[6], v[7]);
        }
      } else {
        const u16b* A = (const u16b*)Ab;
        if (gr < M && gk + 8 <= K) {
          pa[i] = *(const u32x4*)(A + (long)gr * lda + gk);
        } else {
          unsigned v[8];
#pragma unroll
          for (int j = 0; j < 8; ++j)
            v[j] = (gr < M && gk + j < K) ? A[(long)gr * lda + gk + j] : 0u;
          pa[i].x = v[0] | (v[1] << 16); pa[i].y = v[2] | (v[3] << 16);
          pa[i].z = v[4] | (v[5] << 16); pa[i].w = v[6] | (v[7] << 16);
        }
      }
    }
  };
  auto loadB = [&](int k0) {
#pragma unroll
    for (int i = 0; i < NSB; ++i) {
      int si = tid + i * 256;
      int row = si >> 3, c = si & 7;
      int gr = n0 + row, gk = k0 + c * 8;
      if (gr < N && gk + 8 <= K) {
        pb[i] = *(const u32x4*)(Bb + (long)gr * ldb + gk);
      } else {
        unsigned v[8];
#pragma unroll
        for (int j = 0; j < 8; ++j)
          v[j] = (gr < N && gk + j < K) ? Bb[(long)gr * ldb + gk + j] : 0u;
        pb[i].x = v[0] | (v[1] << 16); pb[i].y = v[2] | (v[3] << 16);
        pb[i].z = v[4] | (v[5] << 16); pb[i].w = v[6] | (v[7] << 16);
      }
    }
  };
  auto storeAB = [&]() {
#pragma unroll
    for (int i = 0; i < NSA; ++i) {
      int si = tid + i * 256;
      int row = si >> 3, c = si & 7;
      u32x4 w;
      if constexpr (AF32) {
        float4 u0 = paf[2 * i], u1 = paf[2 * i + 1];
        w.x = pk2bf(u0.x, u0.y); w.y = pk2bf(u0.z, u0.w);
        w.z = pk2bf(u1.x, u1.y); w.w = pk2bf(u1.z, u1.w);
      } else {
        w = pa[i];
      }
      *(u32x4*)&AsU[row * 36 + c * 4] = w;
    }
#pragma unroll
    for (int i = 0; i < NSB; ++i) {
      int si = tid + i * 256;
      int row = si >> 3, c = si & 7;
      *(u32x4*)&BsU[row * 36 + c * 4] = pb[i];
    }
  };

  loadA(0);
  loadB(0);
  storeAB();
  __syncthreads();
  const int nk = CDIV(K, 64);
  for (int t = 0; t < nk; ++t) {
    const bool more = (t + 1 < nk);
    if (more) { loadA((t + 1) * 64); loadB((t + 1) * 64); }
#pragma unroll
    for (int kk = 0; kk < 2; ++kk) {
      u32x4 af[FM], bf[FN];
#pragma unroll
      for (int mi = 0; mi < FM; ++mi)
        af[mi] = *(const u32x4*)&AsU[(wr * (BM / 2) + mi * 16 + fr) * 36 + kk * 16 + fk * 4];
#pragma unroll
      for (int ni = 0; ni < FN; ++ni)
        bf[ni] = *(const u32x4*)&BsU[(wc * (BN / 2) + ni * 16 + fr) * 36 + kk * 16 + fk * 4];
#pragma unroll
      for (int mi = 0; mi < FM; ++mi)
#pragma unroll
        for (int ni = 0; ni < FN; ++ni) mfma_bf16(acc[mi][ni], af[mi], bf[ni]);
    }
    if (more) {
      __syncthreads();
      storeAB();
      __syncthreads();
    }
  }
  asm volatile("s_nop 7\n\ts_nop 7" ::: );
#pragma unroll
  for (int mi = 0; mi < FM; ++mi) {
#pragma unroll
    for (int r = 0; r < 4; ++r) {
      int gm = m0 + wr * (BM / 2) + mi * 16 + fk * 4 + r;
      if (gm >= M) continue;
      float av = addv ? addv[(long)za * (kD * 8) + (long)gm * 8 + zb] : 0.f;
#pragma unroll
      for (int ni = 0; ni < FN; ++ni) {
        int gn = n0 + wc * (BN / 2) + ni * 16 + fr;
        if (gn >= N) continue;
        long idx2 = (long)gm * ldc + gn;
        float v = acc[mi][ni][r] + av;
        C[idx2] = ACC ? (C[idx2] + v) : v;
      }
    }
  }
}

// ---------------- flash attention: O = softmax(30 Q K^T) V, optional lab-dot ------
// 1-D grid, b = blockIdx.x & 7 (XCD-local). K in 16-row panels K8p[z][k16][cs][16][8];
// V in 8-col panels V8[z][c8][kD][8]. All streamed loads 256B-contiguous per fk group.
template <bool LAB, bool KIMG, bool VZ>
__global__ __launch_bounds__(256) void k_flash(const u16b* __restrict__ Q,
                                               const u16b* __restrict__ K8,
                                               const u16b* __restrict__ V8,
                                               const float* __restrict__ labv,
                                               u16b* __restrict__ O,
                                               float* __restrict__ mkout,
                                               int S, int P8, int P16) {
  int orig = blockIdx.x;
  int b = orig & 7;
  int t = orig >> 3;
  int qt0 = (t & 15) * 32;
  int img = t >> 4;
  int z = img * 8 + b;
  int tid = threadIdx.x, wid = tid >> 6, lane = tid & 63;
  int fr = lane & 15, fk = lane >> 4;

  __shared__ float Ssm[32 * 68];
  __shared__ unsigned Plds[32 * 36];
  __shared__ float mrun[32], lrun[32], scal[32], mka[32];

  const long qbase = ((long)img * kR + b) * kKD;
  const long kb8 = (long)(KIMG ? z : b) * P16 * 2048;
  const long vbase = (long)(VZ ? z : b) * P8 * kD * 8;

  u32x4 afq[2][4];
#pragma unroll
  for (int mi = 0; mi < 2; ++mi) {
    int qq = qt0 + mi * 16 + fr;
    if (qq >= kHW) qq = kHW - 1;
#pragma unroll
    for (int kk = 0; kk < 4; ++kk)
      afq[mi][kk] = *(const u32x4*)(Q + qbase + (long)qq * (kB * kKD) + kk * 32 + fk * 8);
  }

  f32x4 oacc[2][8] = {};
  if (tid < 32) { mrun[tid] = -3.0e38f; lrun[tid] = 0.f; mka[tid] = 0.f; }
  __syncthreads();

  int r8 = lane >> 3, i8 = lane & 7;
  int srow = wid * 8 + r8;

  // K double-buffer (panel layout): load tile 0
  u32x4 kcur[4], knxt[4];
  {
    int k16 = wid;
    if (k16 > P16 - 1) k16 = P16 - 1;
    const u16b* kp = K8 + kb8 + (long)k16 * 2048;
#pragma unroll
    for (int kk = 0; kk < 4; ++kk)
      kcur[kk] = *(const u32x4*)(kp + (kk * 4 + fk) * 128 + fr * 8);
  }

  for (int kt = 0; kt < S; kt += 64) {
    // QK^T strip (uses kcur)
    f32x4 sacc[2] = {};
    __builtin_amdgcn_s_setprio(1);
#pragma unroll
    for (int kk = 0; kk < 4; ++kk) {
      mfma_bf16(sacc[0], afq[0][kk], kcur[kk]);
      mfma_bf16(sacc[1], afq[1][kk], kcur[kk]);
    }
    __builtin_amdgcn_s_setprio(0);
    // prefetch THIS tile's V (panel layout)
    u32x4 vreg[2][8];
#pragma unroll
    for (int kk = 0; kk < 2; ++kk) {
      int c8 = (kt >> 3) + kk * 4 + fk;
      if (c8 > P8 - 1) c8 = P8 - 1;
      const u16b* vp = V8 + vbase + (long)c8 * kD * 8;
#pragma unroll
      for (int n = 0; n < 8; ++n) {
        int d = wid * 128 + n * 16 + fr;
        vreg[kk][n] = *(const u32x4*)(vp + (long)d * 8);
      }
    }
    // prefetch NEXT tile's K (panel layout)
    const bool more = (kt + 64 < S);
    if (more) {
      int k16n = ((kt + 64) >> 4) + wid;
      if (k16n > P16 - 1) k16n = P16 - 1;
      const u16b* kp2 = K8 + kb8 + (long)k16n * 2048;
#pragma unroll
      for (int kk = 0; kk < 4; ++kk)
        knxt[kk] = *(const u32x4*)(kp2 + (kk * 4 + fk) * 128 + fr * 8);
    }
    asm volatile("s_nop 7\n\ts_nop 7" ::: );  // MFMA -> VALU hazard
    {
      int krow = kt + wid * 16 + fr;
      if (krow >= S) {
#pragma unroll
        for (int mi = 0; mi < 2; ++mi)
#pragma unroll
          for (int r = 0; r < 4; ++r) sacc[mi][r] = -1.0e30f;
      }
#pragma unroll
      for (int mi = 0; mi < 2; ++mi)
#pragma unroll
        for (int r = 0; r < 4; ++r)
          Ssm[(mi * 16 + fk * 4 + r) * 68 + wid * 16 + fr] = sacc[mi][r];
    }
    ldsbar();  // B1: Ssm RAW (lgkm-only)
    // online softmax
    {
      float v[8];
      float mx = -3.0e38f;
#pragma unroll
      for (int j = 0; j < 8; ++j) {
        v[j] = Ssm[srow * 68 + i8 * 8 + j] * kTemp;
        mx = fmaxf(mx, v[j]);
      }
#pragma unroll
      for (int o = 1; o < 8; o <<= 1) mx = fmaxf(mx, __shfl_xor(mx, o));
      float mold = mrun[srow];
      float mnew = fmaxf(mold, mx);
      float p[8], ts = 0.f, lacc = 0.f;
#pragma unroll
      for (int j = 0; j < 8; ++j) {
        p[j] = __expf(v[j] - mnew);
        ts += p[j];
        if (LAB) {
          int kidx = kt + i8 * 8 + j;
          lacc += p[j] * labv[(long)(kidx < S ? kidx : S - 1) * kB + b];
        }
      }
#pragma unroll
      for (int o = 1; o < 8; o <<= 1) ts += __shfl_xor(ts, o);
      if (LAB) {
#pragma unroll
        for (int o = 1; o < 8; o <<= 1) lacc += __shfl_xor(lacc, o);
      }
      u32x4 w0;
      w0.x = pk2bf(p[0], p[1]); w0.y = pk2bf(p[2], p[3]);
      w0.z = pk2bf(p[4], p[5]); w0.w = pk2bf(p[6], p[7]);
      *(u32x4*)&Plds[srow * 36 + i8 * 4] = w0;
      if (i8 == 0) {
        float sc = __expf(mold - mnew);
        mrun[srow] = mnew;
        lrun[srow] = lrun[srow] * sc + ts;
        scal[srow] = sc;
        if (LAB) mka[srow] = mka[srow] * sc + lacc;
      }
    }
    ldsbar();  // B2: Plds + scal RAW (lgkm-only)
    // rescale O (VALU), then PV (MFMA reads oacc as SrcC)
#pragma unroll
    for (int mi = 0; mi < 2; ++mi)
#pragma unroll
      for (int r = 0; r < 4; ++r) {
        float sc = scal[mi * 16 + fk * 4 + r];
#pragma unroll
        for (int n = 0; n < 8; ++n) oacc[mi][n][r] *= sc;
      }
    asm volatile("s_nop 7" ::: );  // VALU write -> MFMA SrcC read hazard
    __builtin_amdgcn_s_setprio(1);
#pragma unroll
    for (int kk = 0; kk < 2; ++kk) {
      u32x4 ap0 = *(const u32x4*)&Plds[fr * 36 + kk * 16 + fk * 4];
      u32x4 ap1 = *(const u32x4*)&Plds[(16 + fr) * 36 + kk * 16 + fk * 4];
#pragma unroll
      for (int n = 0; n < 8; ++n) {
        mfma_bf16(oacc[0][n], ap0, vreg[kk][n]);
        mfma_bf16(oacc[1][n], ap1, vreg[kk][n]);
      }
    }
    __builtin_amdgcn_s_setprio(0);
    asm volatile("s_nop 7\n\ts_nop 7" ::: );  // MFMA -> VALU
    if (more) {
#pragma unroll
      for (int kk = 0; kk < 4; ++kk) kcur[kk] = knxt[kk];
    }
  }
  asm volatile("s_nop 7\n\ts_nop 7" ::: );
  __syncthreads();  // final full barrier before epilogue
#pragma unroll
  for (int mi = 0; mi < 2; ++mi)
#pragma unroll
    for (int r = 0; r < 4; ++r) {
      int qq = mi * 16 + fk * 4 + r;
      int gq = qt0 + qq;
      if (gq >= kHW) continue;
      float invl = 1.0f / lrun[qq];
      long orow = ((long)img * kR + (long)gq * kB + b) * kD;
#pragma unroll
      for (int n = 0; n < 8; ++n)
        O[orow + wid * 128 + n * 16 + fr] = f2bf(oacc[mi][n][r] * invl);
    }
  if (LAB && tid < 32) {
    int gq = qt0 + tid;
    if (gq < kHW) mkout[(long)img * kR + (long)gq * kB + b] = mka[tid] / lrun[tid];
  }
}

// row += bias; l2-normalize; fp32 in place + bf16 mirror; optional g = u.row
__global__ void k_bias_l2n(float* __restrict__ P, const float* __restrict__ bias, int C,
                           u16b* __restrict__ outb, const float* __restrict__ u,
                           float* __restrict__ g, int L) {
  __shared__ float red[2];
  long row = blockIdx.x;
  float* p = P + row * C;
  int tid = threadIdx.x;  // 128
  int nv = C >> 7;
  float v[4];
  float s = 0.f;
#pragma unroll
  for (int i = 0; i < 4; ++i)
    if (i < nv) {
      float x = p[tid + (i << 7)] + bias[tid + (i << 7)];
      v[i] = x;
      s += x * x;
    }
  s = wsum(s);
  if ((tid & 63) == 0) red[tid >> 6] = s;
  __syncthreads();
  float inv = 1.f / fmaxf(sqrtf(red[0] + red[1]), 1e-12f);
  float dot = 0.f;
#pragma unroll
  for (int i = 0; i < 4; ++i)
    if (i < nv) {
      float x = v[i] * inv;
      p[tid + (i << 7)] = x;
      outb[row * C + tid + (i << 7)] = f2bf(x);
      if (u) dot += x * u[tid + (i << 7)];
    }
  if (u) {
    __syncthreads();
    dot = wsum(dot);
    if ((tid & 63) == 0) red[tid >> 6] = dot;
    __syncthreads();
    if (tid == 0) {
      int img = (int)(row / kR);
      int within = (int)(row % kR);
      int qq = within >> 3, b = within & 7;
      g[((long)(img * 8 + b)) * L + qq] = red[0] + red[1];
    }
  }
}

// generic softmax; optional bf16 out at row*ldo
__global__ __launch_bounds__(256) void k_softmax(float* __restrict__ S, int Lq, int Lk,
                                                 u16b* __restrict__ outb, int ldo) {
  __shared__ float sm[1456];
  __shared__ float red[4];
  int row = blockIdx.x;
  float* Sr = S + (long)row * Lk;
  int tid = threadIdx.x;
  float mx = -3.0e38f;
  for (int k = tid; k < Lk; k += 256) {
    float v = Sr[k] * kTemp;
    sm[k] = v;
    mx = fmaxf(mx, v);
  }
  mx = wmax(mx);
  if ((tid & 63) == 0) red[tid >> 6] = mx;
  __syncthreads();
  mx = fmaxf(fmaxf(red[0], red[1]), fmaxf(red[2], red[3]));
  __syncthreads();
  float s = 0.f;
  for (int k = tid; k < Lk; k += 256) {
    float e = __expf(sm[k] - mx);
    sm[k] = e;
    s += e;
  }
  s = wsum(s);
  if ((tid & 63) == 0) red[tid >> 6] = s;
  __syncthreads();
  float inv = 1.0f / (red[0] + red[1] + red[2] + red[3]);
  for (int k = tid; k < Lk; k += 256) {
    float p = sm[k] * inv;
    if (outb) outb[(long)row * ldo + k] = f2bf(p); else Sr[k] = p;
  }
}

// fused cR + softmax + lab-dot: block z in [0,48)
__global__ __launch_bounds__(256) void k_cwi(const float* __restrict__ vb,
                                             const u16b* __restrict__ Krb,
                                             const float* __restrict__ labv,
                                             float* __restrict__ wI,
                                             float* __restrict__ mki8) {
  __shared__ float sm[kL];
  __shared__ float vbl[kKD];
  __shared__ float red[4];
  int z = blockIdx.x, b = z & 7;
  int tid = threadIdx.x;
  if (tid < kKD) vbl[tid] = vb[(long)z * kKD + tid];
  __syncthreads();
  float mx = -3.0e38f;
  for (int k = tid; k < kL; k += 256) {
    const u16b* kp = Krb + ((long)k * kB + b) * kKD;
    float s = 0.f;
    for (int c = 0; c < kKD; c += 8) {
      u32x4 w = *(const u32x4*)(kp + c);
      s += vbl[c] * bf2f((u16b)(w.x & 0xFFFF)) + vbl[c + 1] * bf2f((u16b)(w.x >> 16));
      s += vbl[c + 2] * bf2f((u16b)(w.y & 0xFFFF)) + vbl[c + 3] * bf2f((u16b)(w.y >> 16));
      s += vbl[c + 4] * bf2f((u16b)(w.z & 0xFFFF)) + vbl[c + 5] * bf2f((u16b)(w.z >> 16));
      s += vbl[c + 6] * bf2f((u16b)(w.w & 0xFFFF)) + vbl[c + 7] * bf2f((u16b)(w.w >> 16));
    }
    sm[k] = s * kTemp;
    mx = fmaxf(mx, sm[k]);
  }
  mx = wmax(mx);
  if ((tid & 63) == 0) red[tid >> 6] = mx;
  __syncthreads();
  mx = fmaxf(fmaxf(red[0], red[1]), fmaxf(red[2], red[3]));
  __syncthreads();
  float s = 0.f;
  for (int k = tid; k < kL; k += 256) {
    float e = __expf(sm[k] - mx);
    sm[k] = e;
    s += e;
  }
  s = wsum(s);
  if ((tid & 63) == 0) red[tid >> 6] = s;
  __syncthreads();
  float inv = 1.0f / (red[0] + red[1] + red[2] + red[3]);
  __syncthreads();
  float dot = 0.f;
  for (int k = tid; k < kL; k += 256) {
    float p = sm[k] * inv;
    wI[(long)z * kL + k] = p;
    dot += p * labv[(long)k * kB + b];
  }
  dot = wsum(dot);
  if ((tid & 63) == 0) red[tid >> 6] = dot;
  __syncthreads();
  if (tid == 0) mki8[z] = red[0] + red[1] + red[2] + red[3];
}

// deterministic rank-1 AV, phase A
__global__ void k_wrowA(const float* __restrict__ g, const float* __restrict__ seq,
                        float* __restrict__ row2) {
  int z = blockIdx.y, img = z >> 3, b = z & 7;
  int c = blockIdx.z;
  int d = blockIdx.x * 128 + threadIdx.x;
  int k0 = c * 61;
  int k1 = min(kHW, k0 + 61);
  float s = 0.f;
  for (int k = k0; k < k1; ++k)
    s += g[(long)z * kHW + k] * seq[((long)img * kR + (long)k * kB + b) * kD + d];
  row2[((long)z * 8 + c) * kD + d] = s;
}

// phase B: row[z*kD+d] = sum_c row2 (fixed order)
__global__ void k_wrowB(const float* __restrict__ row2, float* __restrict__ row) {
  int idx = blockIdx.x * 256 + threadIdx.x;
  int z = idx >> 9, d = idx & 511;
  float s = 0.f;
#pragma unroll
  for (int c = 0; c < 8; ++c) s += row2[((long)z * 8 + c) * kD + d];
  row[(long)z * kD + d] = s;
}

// fp32 inorm phase 1 (encoder)
__global__ __launch_bounds__(256) void k_ss1f(const float* __restrict__ A,
                                              const float* __restrict__ B2,
                                              float* __restrict__ part) {
  __shared__ float red[4];
  long r = blockIdx.x;
  int tid = threadIdx.x;
  long base = r * kD;
  float z0 = A[base + tid] + B2[base + tid];
  float z1 = A[base + tid + 256] + B2[base + tid + 256];
  float s = z0 * z0 + z1 * z1;
  s = wsum(s);
  if ((tid & 63) == 0) red[tid >> 6] = s;
  __syncthreads();
  if (tid == 0) part[r] = red[0] + red[1] + red[2] + red[3];
}

// fp32 inorm phase 3 (encoder): fp32 out + bf16 mirror
__global__ __launch_bounds__(256) void k_scale1f(const float* __restrict__ A,
                                                 const float* __restrict__ B2,
                                                 float* __restrict__ outp,
                                                 const float* __restrict__ ss,
                                                 u16b* __restrict__ ob) {
  long r = blockIdx.x;
  int l = (int)(r / kB), b = (int)(r % kB);
  int g = (l / kHW) * kB + b;
  int tid = threadIdx.x;
  float fac = kScaleN * sqrtf(kCnt / (ss[g] + 1e-5f));
  long base = r * kD;
  float x0 = (A[base + tid] + B2[base + tid]) * fac;
  float x1 = (A[base + tid + 256] + B2[base + tid + 256]) * fac;
  outp[base + tid] = x0;
  outp[base + tid + 256] = x1;
  ob[base + tid] = f2bf(x0);
  ob[base + tid + 256] = f2bf(x1);
}

// t1 inorm, phase 1 (B2 bf16)
__global__ __launch_bounds__(256) void k_ss1b(const float* __restrict__ A,
                                              const u16b* __restrict__ B2,
                                              float* __restrict__ part) {
  __shared__ float red[4];
  long r = blockIdx.x;
  int tid = threadIdx.x;
  long base = r * kD;
  float z0 = A[base + tid] + bf2f(B2[base + tid]);
  float z1 = A[base + tid + 256] + bf2f(B2[base + tid + 256]);
  float s = z0 * z0 + z1 * z1;
  s = wsum(s);
  if ((tid & 63) == 0) red[tid >> 6] = s;
  __syncthreads();
  if (tid == 0) part[r] = red[0] + red[1] + red[2] + red[3];
}

__global__ void k_ssred(const float* __restrict__ part, float* __restrict__ ss, int R, int NG) {
  __shared__ float red[8];
  int g = blockIdx.x, v = blockIdx.y;
  int n = g / kB, b = g % kB;
  int tid = threadIdx.x;  // 512
  float s = 0.f;
  for (int p = tid; p < kHW; p += 512) s += part[(long)v * R + ((long)(n * kHW + p) * kB + b)];
  s = wsum(s);
  if ((tid & 63) == 0) red[tid >> 6] = s;
  __syncthreads();
  if (tid == 0) {
    float t = 0.f;
#pragma unroll
    for (int i = 0; i < 8; ++i) t += red[i];
    ss[(long)v * NG + g] = t;
  }
}

// t1 inorm, phase 3 -> bf16 only
__global__ __launch_bounds__(256) void k_scale1b(const float* __restrict__ A,
                                                 const u16b* __restrict__ B2,
                                                 const float* __restrict__ ss,
                                                 u16b* __restrict__ ob) {
  long r = blockIdx.x;
  int img = (int)(r / kR), b = (int)(r & 7);
  int g = img * 8 + b;
  int tid = threadIdx.x;
  float fac = kScaleN * sqrtf(kCnt / (ss[g] + 1e-5f));
  long base = r * kD;
  ob[base + tid] = f2bf((A[base + tid] + bf2f(B2[base + tid])) * fac);
  ob[base + tid + 256] = f2bf((A[base + tid + 256] + bf2f(B2[base + tid + 256])) * fac);
}

// ti8[z,d] = row[z,d] * scale(kHW * ||row||^2)
__global__ void k_ti8(const float* __restrict__ row, float* __restrict__ ti8) {
  __shared__ float red[4];
  int z = blockIdx.x;
  int tid = threadIdx.x;  // 256
  float r0 = row[(long)z * kD + tid], r1 = row[(long)z * kD + tid + 256];
  float s = r0 * r0 + r1 * r1;
  s = wsum(s);
  if ((tid & 63) == 0) red[tid >> 6] = s;
  __syncthreads();
  float ssv = (float)kHW * (red[0] + red[1] + red[2] + red[3]);
  float fac = kScaleN * sqrtf(kCnt / (ssv + 1e-5f));
  ti8[(long)z * kD + tid] = r0 * fac;
  ti8[(long)z * kD + tid + 256] = r1 * fac;
}

// vb[z,:] = l2n(ti8_z @ WkC + bkC)
__global__ void k_vb(const float* __restrict__ ti8, const float* __restrict__ Wk,
                     const float* __restrict__ bk, float* __restrict__ vb) {
  __shared__ float part[4][128];
  __shared__ float red[2];
  int z = blockIdx.x;
  int j = threadIdx.x;
  int dz = threadIdx.y;
  const float* row = ti8 + (long)z * kD;
  float acc = 0.f;
  int d0 = dz * 128;
  for (int d = d0; d < d0 + 128; ++d) acc += row[d] * Wk[(long)d * kKD + j];
  part[dz][j] = acc;
  __syncthreads();
  if (dz == 0) {
    float a = part[0][j] + part[1][j] + part[2][j] + part[3][j] + bk[j];
    float s = a * a;
    s = wsum(s);
    if ((j & 63) == 0) red[j >> 6] = s;
    part[0][j] = a;
  }
  __syncthreads();
  if (dz == 0) {
    float inv = 1.f / fmaxf(sqrtf(red[0] + red[1]), 1e-12f);
    vb[(long)z * kKD + j] = part[0][j] * inv;
  }
}

// ci8[z,d] = sum_l wI[z,l] * VrT[b][d][l]
__global__ void k_ci8(const float* __restrict__ wI, const u16b* __restrict__ VrT,
                      float* __restrict__ ci8) {
  int idx = blockIdx.x * 4 + (threadIdx.x >> 6);
  int z = idx >> 9, d = idx & 511;
  int b = z & 7;
  int lane = threadIdx.x & 63;
  const float* w = wI + (long)z * kL;
  const u16b* vt = VrT + ((long)b * kD + d) * kLp;
  float s = 0.f;
  for (int l = lane; l < kL; l += 64) s += w[l] * bf2f(vt[l]);
  s = wsum(s);
  if (lane == 0) ci8[(long)z * kD + d] = s;
}

// tail partials: v in {a^2, b^2, ab}, a = t1*mk, b = t1 + c3 (bf16 inputs)
__global__ __launch_bounds__(256) void k_ss3b(const u16b* __restrict__ t1b,
                                              const float* __restrict__ mkr,
                                              const u16b* __restrict__ c3b,
                                              float* __restrict__ part) {
  __shared__ float red[4][3];
  long r = blockIdx.x;
  int tid = threadIdx.x;
  long base = r * kD;
  float mk = mkr[r];
  float s0 = 0.f, s1 = 0.f, s2 = 0.f;
#pragma unroll
  for (int j = 0; j < 2; ++j) {
    int d = tid + j * 256;
    float t = bf2f(t1b[base + d]);
    float a = t * mk;
    float bb = t + bf2f(c3b[base + d]);
    s0 += a * a; s1 += bb * bb; s2 += a * bb;
  }
  int w = tid >> 6, lane = tid & 63;
  float t0 = wsum(s0), t1 = wsum(s1), t2 = wsum(s2);
  if (lane == 0) { red[w][0] = t0; red[w][1] = t1; red[w][2] = t2; }
  __syncthreads();
  if (tid < 3)
    part[(long)tid * kR6 + r] = red[0][tid] + red[1][tid] + red[2][tid] + red[3][tid];
}

// per-image coefficients + oi8 (imag analytic)
__global__ __launch_bounds__(512) void k_coef(const float* __restrict__ ssp,
                                              const float* __restrict__ ti8,
                                              const float* __restrict__ ci8,
                                              const float* __restrict__ mki8,
                                              float* __restrict__ coef,
                                              float* __restrict__ oi8) {
  __shared__ float cai[8], cbi[8];
  int img = blockIdx.x;
  int tid = threadIdx.x;
  int b = tid >> 6, lane = tid & 63;
  int z = img * 8 + b;
  float sT = 0.f, sU = 0.f, sV = 0.f;
  for (int d = lane; d < kD; d += 64) {
    float ti = ti8[(long)z * kD + d], ci = ci8[(long)z * kD + d];
    float u = ti + ci;
    sT += ti * ti; sU += u * u; sV += ti * u;
  }
  sT = wsum(sT); sU = wsum(sU); sV = wsum(sV);
  if (lane == 0) {
    float SSa = ssp[z], SSb = ssp[48 + z], SSab = ssp[96 + z];
    float f2 = kScaleN * sqrtf(kCnt / (SSa + 1e-5f));
    float f4 = kScaleN * sqrtf(kCnt / (SSb + 1e-5f));
    float ssz = f2 * f2 * SSa + f4 * f4 * SSb + 2.f * f2 * f4 * SSab;
    float fac = kScaleN * sqrtf(kCnt / (ssz + 1e-5f));
    coef[img * 16 + b] = f2 * fac;
    coef[img * 16 + 8 + b] = f4 * fac;
    float mk = mki8[z];
    float SSai = (float)kHW * mk * mk * sT;
    float SSbi = (float)kHW * sU;
    float SSabi = (float)kHW * mk * sV;
    float f2i = kScaleN * sqrtf(kCnt / (SSai + 1e-5f));
    float f4i = kScaleN * sqrtf(kCnt / (SSbi + 1e-5f));
    float sszi = f2i * f2i * SSai + f4i * f4i * SSbi + 2.f * f2i * f4i * SSabi;
    float faci = kScaleN * sqrtf(kCnt / (sszi + 1e-5f));
    cai[b] = f2i * faci;
    cbi[b] = f4i * faci;
  }
  __syncthreads();
#pragma unroll
  for (int j = 0; j < 8; ++j) {
    int i = tid * 8 + j;
    int bb = i >> 9, d = i & 511;
    int zz = img * 8 + bb;
    float ti = ti8[(long)zz * kD + d], ci = ci8[(long)zz * kD + d];
    oi8[(long)img * 4096 + i] = ti * mki8[zz] * cai[bb] + (ti + ci) * cbi[bb];
  }
}

// oadd[img][o*8+b] = Wc_imag_row(o) . oi8[img*8+b]
__global__ void k_oadd(const float* __restrict__ Wc, const float* __restrict__ oi8,
                       float* __restrict__ oadd) {
  int idx = blockIdx.x * 4 + (threadIdx.x >> 6);
  int img = idx >> 12, rem = idx & 4095;
  int o = rem >> 3, b = rem & 7;
  int lane = threadIdx.x & 63;
  const float* wrow = Wc + (long)o * 1024 + 512;
  const float* oi = oi8 + (long)img * 4096 + (long)b * kD;
  float s = 0.f;
  for (int d = lane; d < kD; d += 64) s += wrow[d] * oi[d];
  s = wsum(s);
  if (lane == 0) oadd[(long)img * 4096 + o * 8 + b] = s;
}

// t2b[r][d] = bf16( t1*mk*ca + (t1+c3)*cb )
__global__ __launch_bounds__(256) void k_zfinb(const u16b* __restrict__ t1b,
                                               const float* __restrict__ mkr,
                                               const u16b* __restrict__ c3b,
                                               const float* __restrict__ coef,
                                               u16b* __restrict__ t2b) {
  long r = blockIdx.x;
  int img = (int)(r / kR), b = (int)(r & 7);
  int tid = threadIdx.x;
  float mk = mkr[r];
  float ca = coef[img * 16 + b], cb = coef[img * 16 + 8 + b];
  long base = r * kD;
#pragma unroll
  for (int j = 0; j < 2; ++j) {
    int d = tid + j * 256;
    float t = bf2f(t1b[base + d]);
    float ov = t * mk * ca + (t + bf2f(c3b[base + d])) * cb;
    t2b[base + d] = f2bf(ov);
  }
}

template <int BM, int BN, bool AF32, bool ACC>
void gemm(hipStream_t s, const void* A, const u16b* B, float* C, int M, int N, int K, int lda,
          int ldb, int ldc, long sA1, long sA2, long sB1, long sB2, long sC1, long sC2,
          int batch, const float* addv = nullptr) {
  dim3 grd(CDIV(N, BN), CDIV(M, BM), batch), blk(256);
  k_gemm<BM, BN, AF32, ACC><<<grd, blk, 0, s>>>(A, B, C, M, N, K, lda, ldb, ldc, sA1, sA2,
                                                sB1, sB2, sC1, sC2, addv);
}

}  // namespace

extern "C" void kernel_launch(void* const* d_in, const int* in_sizes, int n_in, void* d_out,
                              int out_size, void* d_ws, size_t ws_size, hipStream_t stream) {
  (void)in_sizes; (void)n_in; (void)out_size;
  const float* tf  = (const float*)d_in[0];
  const float* sf  = (const float*)d_in[1];
  const float* tl  = (const float*)d_in[2];
  const float* WkE = (const float*)d_in[3];
  const float* bkE = (const float*)d_in[4];
  const float* WkS = (const float*)d_in[5];
  const float* bkS = (const float*)d_in[6];
  const float* WkC = (const float*)d_in[7];
  const float* bkC = (const float*)d_in[8];
  const float* Wc  = (const float*)d_in[9];
  float* out = (float*)d_out;
  float* ws = (float*)d_ws;

  const long LBD = (long)kL * kB * kD;
  const long LBK = (long)kL * kB * kKD;

  long off = 0;
  auto alloc = [&](long n) { long o = off; off += (n + 255) & ~255L; return o; };
  auto allocU = [&](long nu) { return alloc((nu + 1) / 2); };

  long o_seqT = alloc(LBD);
  long o_seqS = alloc(LBD);
  long o_Kr   = alloc(LBK);
  long o_Krb  = allocU(LBK);
  long o_VrT  = allocU((long)kB * kD * kLp);
  long o_tfb  = allocU((long)kNI * kB * kD * kHWp);
  long o_sfb  = allocU((long)kNI * kB * kD * kHWp);
  long o_WkTE = allocU((long)kD * kD);
  long o_WkTS = allocU((long)kKD * kD);
  long o_WkTC = allocU((long)kKD * kD);
  long o_Wcb  = allocU((long)kD * 2 * kD);
  long o_lab  = alloc((long)kL * kB);
  long o_uS   = alloc(kKD);
  long o_vb   = alloc(48L * kKD);
  long o_g    = alloc(48L * kHW);
  long o_wI   = alloc(48L * kL);
  long o_row  = alloc(48L * kD);
  long o_row2 = alloc(48L * 8 * kD);
  long o_mkr  = alloc((long)kR6);
  long o_mki8 = alloc(48);
  long o_ti8  = alloc(48L * kD);
  long o_ci8  = alloc(48L * kD);
  long o_oi8  = alloc(48L * kD);
  long o_oadd = alloc(6L * kD * 8);
  long o_ss   = alloc(512);
  long o_part = alloc(3L * kR6);
  long o_scr  = off;

  // encoder overlay
  long o_Pe  = o_scr;
  long o_Peb = o_Pe + LBD;
  long o_Ae  = o_Peb + LBD / 2;
  long o_Aeb = o_Ae + (long)kB * kL * kL;
  long enc_end = o_Aeb + (8L * kL * kLp + 1) / 2;
  long o_ar  = o_Pe;   // after Pe dead
  long o_mr  = o_Ae;   // after Ae dead

  // decoder overlay (batched over 6 images)
  long p = o_scr;
  auto nxt = [&](long n) { long o = p; p += (n + 255) & ~255L; return o; };
  long o_Ps   = nxt((long)kR6 * kKD);
  long o_Psb  = nxt(((long)kR6 * kKD + 1) / 2);
  long o_Pcb  = nxt(((long)kR6 * kKD + 1) / 2);
  long o_s2rb = nxt(((long)kR6 * kD + 1) / 2);
  long o_t1rb = nxt(((long)kR6 * kD + 1) / 2);
  long o_c3rb = nxt(((long)kR6 * kD + 1) / 2);
  long o_t2b  = nxt(((long)kR6 * kD + 1) / 2);
  long o_V8s  = nxt((48L * kP8s * kD * 8 + 1) / 2);
  long o_V8c  = nxt((8L * kP8c * kD * 8 + 1) / 2);
  long o_K8s  = nxt((48L * kP16s * 2048 + 1) / 2);
  long o_K8c  = nxt((8L * kP16c * 2048 + 1) / 2);
  long img_end = p;

  long total = (enc_end > img_end ? enc_end : img_end);
  if ((size_t)total * sizeof(float) > ws_size) return;

  float* seqT = ws + o_seqT;
  float* Kr = ws + o_Kr;
  u16b* Krb = (u16b*)(ws + o_Krb);
  u16b* VrT = (u16b*)(ws + o_VrT);
  u16b* tfb = (u16b*)(ws + o_tfb);
  float* lab = ws + o_lab;
  float* uS = ws + o_uS;
  float* vb = ws + o_vb;
  float* g_ = ws + o_g;
  float* wI = ws + o_wI;
  float* row = ws + o_row;
  float* row2 = ws + o_row2;
  float* mkr = ws + o_mkr;
  float* mki8 = ws + o_mki8;
  float* ti8 = ws + o_ti8;
  float* ci8 = ws + o_ci8;
  float* oi8 = ws + o_oi8;
  float* oadd = ws + o_oadd;
  float* ssp = ws + o_ss;
  float* coef = ssp + 160;
  float* part = ws + o_part;
  float* Pe = ws + o_Pe;
  u16b* Peb = (u16b*)(ws + o_Peb);
  float* Ae = ws + o_Ae;
  u16b* Aeb = (u16b*)(ws + o_Aeb);
  float* ar = ws + o_ar;
  float* mr = ws + o_mr;
  u16b* mrb = (u16b*)(ws + o_mr + LBD);
  float* Ps = ws + o_Ps;
  u16b* Psb = (u16b*)(ws + o_Psb);
  u16b* Pcb = (u16b*)(ws + o_Pcb);
  u16b* s2rb = (u16b*)(ws + o_s2rb);
  u16b* t1rb = (u16b*)(ws + o_t1rb);
  u16b* c3rb = (u16b*)(ws + o_c3rb);
  u16b* t2b = (u16b*)(ws + o_t2b);
  u16b* V8s = (u16b*)(ws + o_V8s);
  u16b* V8c = (u16b*)(ws + o_V8c);
  u16b* K8s = (u16b*)(ws + o_K8s);
  u16b* K8c = (u16b*)(ws + o_K8c);
  u16b* WkTE = (u16b*)(ws + o_WkTE);
  u16b* WkTS = (u16b*)(ws + o_WkTS);
  u16b* WkTC = (u16b*)(ws + o_WkTC);
  u16b* Wcb = (u16b*)(ws + o_Wcb);

  // ---- stage 0 ----
  {
    dim3 grd(CDIV(kHW, 32), CDIV(kD, 32), kNI * kB), blk(32, 8);
    k_toseq<<<grd, blk, 0, stream>>>(tf, seqT);
    k_toseq<<<grd, blk, 0, stream>>>(sf, ws + o_seqS);
  }
  k_cvt2d<<<kNI * kB * kD, 256, 0, stream>>>(tf, tfb, kHW, kHWp);
  k_cvt2d<<<kNI * kB * kD, 256, 0, stream>>>(sf, (u16b*)(ws + o_sfb), kHW, kHWp);
  k_cvt2d<<<kD, 256, 0, stream>>>(Wc, Wcb, 2 * kD, 2 * kD);
  k_tcvt<<<dim3(kD / 32, kD / 32), dim3(32, 8), 0, stream>>>(WkE, WkTE, kD, kD);
  k_tcvt<<<dim3(kKD / 32, kD / 32), dim3(32, 8), 0, stream>>>(WkS, WkTS, kD, kKD);
  k_tcvt<<<dim3(kKD / 32, kD / 32), dim3(32, 8), 0, stream>>>(WkC, WkTC, kD, kKD);
  k_lab<<<CDIV(kNI * kB * kHW, 256), 256, 0, stream>>>(tl, lab);
  k_l2n_vec<<<1, 128, 0, stream>>>(bkS, uS, kKD);

  // ---- encoder (imag branch dead) ----
  gemm<64, 128, true, false>(stream, seqT, WkTE, Pe, kL * kB, kD, kD, kD, kD, kD,
                             0, 0, 0, 0, 0, 0, 1);
  k_bias_l2n<<<kL * kB, 128, 0, stream>>>(Pe, bkE, kD, Peb, nullptr, nullptr, 0);
  gemm<128, 128, false, false>(stream, Peb, Peb, Ae, kL, kL, kD, kB * kD, kB * kD, kL,
                               0, kD, 0, kD, 0, (long)kL * kL, 8);
  k_softmax<<<kB * kL, 256, 0, stream>>>(Ae, kL, kL, Aeb, kLp);
  gemm<64, 128, false, false>(stream, Aeb, tfb, ar, kL, kD, kHW, kLp, kHWp, kB * kD,
                              0, (long)kL * kLp, 0, (long)kD * kHWp, 0, kD, 8);
  gemm<64, 128, false, true>(stream, Aeb + kHW, tfb + (long)kB * kD * kHWp, ar, kL, kD, kHW,
                             kLp, kHWp, kB * kD, 0, (long)kL * kLp, 0, (long)kD * kHWp, 0, kD,
                             8);
  gemm<64, 128, false, true>(stream, Aeb + 2 * kHW, tfb + 2L * kB * kD * kHWp, ar, kL, kD,
                             kHW, kLp, kHWp, kB * kD, 0, (long)kL * kLp, 0, (long)kD * kHWp,
                             0, kD, 8);
  // mem_r = inorm(seqT + ar)
  k_ss1f<<<kL * kB, 256, 0, stream>>>(seqT, ar, part);
  k_ssred<<<dim3(kNI * kB, 1), 512, 0, stream>>>(part, ssp, kL * kB, kNI * kB);
  k_scale1f<<<kL * kB, 256, 0, stream>>>(seqT, ar, mr, ssp, mrb);
  k_vrt<<<dim3(CDIV(kL, 32), kD / 32, kB), dim3(32, 8), 0, stream>>>(mr, lab, VrT);
  gemm<64, 64, false, false>(stream, mrb, WkTC, Kr, kL * kB, kKD, kD, kD, kD, kKD,
                             0, 0, 0, 0, 0, 0, 1);
  k_bias_l2n<<<kL * kB, 128, 0, stream>>>(Kr, bkC, kKD, Krb, nullptr, nullptr, 0);

  // ---- decoder (fully batched over 48 = 6 img x 8 b) ----
  // V / K panel repacks (decoder overlay region)
  k_vpack<<<48 * kP8s * kD * 8 / 256, 256, 0, stream>>>(tfb, V8s, kHWp, kP8s, kHW);
  k_vpack<<<8 * kP8c * kD * 8 / 256, 256, 0, stream>>>(VrT, V8c, kLp, kP8c, kL);
  k_kpack<<<8 * kP16c * 2048 / 256, 256, 0, stream>>>(Krb, K8c, kP16c, kL, 0);
  gemm<64, 128, true, false>(stream, seqT, WkTS, Ps, kR6, kKD, kD, kD, kD, kKD,
                             0, 0, 0, 0, 0, 0, 1);
  k_bias_l2n<<<kR6, 128, 0, stream>>>(Ps, bkS, kKD, Psb, uS, g_, kHW);
  k_kpack<<<48 * kP16s * 2048 / 256, 256, 0, stream>>>(Psb, K8s, kP16s, kHW, kR);
  k_softmax<<<48, 256, 0, stream>>>(g_, 1, kHW, nullptr, 0);  // wi rows
  k_wrowA<<<dim3(kD / 128, 48, 8), 128, 0, stream>>>(g_, seqT, row2);
  k_wrowB<<<48 * kD / 256, 256, 0, stream>>>(row2, row);
  k_ti8<<<48, 256, 0, stream>>>(row, ti8);
  k_vb<<<48, dim3(128, 4), 0, stream>>>(ti8, WkC, bkC, vb);
  // self-attention flash: s2r (packed K + V)
  k_flash<false, true, true><<<768, 256, 0, stream>>>(Psb, K8s, V8s, nullptr, s2rb,
                                                      nullptr, kHW, kP8s, kP16s);
  // t1r = inorm(t + s2r) -> bf16
  k_ss1b<<<kR6, 256, 0, stream>>>(seqT, s2rb, part);
  k_ssred<<<dim3(48, 1), 512, 0, stream>>>(part, ssp, kR6, 48);
  k_scale1b<<<kR6, 256, 0, stream>>>(seqT, s2rb, ssp, t1rb);
  // cross projection
  gemm<64, 128, false, false>(stream, t1rb, WkTC, Ps, kR6, kKD, kD, kD, kD, kKD,
                              0, 0, 0, 0, 0, 0, 1);
  k_bias_l2n<<<kR6, 128, 0, stream>>>(Ps, bkC, kKD, Pcb, nullptr, nullptr, 0);
  // imag branch (q-independent)
  k_cwi<<<48, 256, 0, stream>>>(vb, Krb, lab, wI, mki8);
  k_ci8<<<48 * 512 / 4, 256, 0, stream>>>(wI, VrT, ci8);
  // cross flash: c3r + mkr (packed K + V)
  k_flash<true, false, false><<<768, 256, 0, stream>>>(Pcb, K8c, V8c, lab, c3rb,
                                                       mkr, kL, kP8c, kP16c);
  // fused tail
  k_ss3b<<<kR6, 256, 0, stream>>>(t1rb, mkr, c3rb, part);
  k_ssred<<<dim3(48, 3), 512, 0, stream>>>(part, ssp, kR6, 48);
  k_coef<<<6, 512, 0, stream>>>(ssp, ti8, ci8, mki8, coef, oi8);
  k_oadd<<<6 * 4096 / 4, 256, 0, stream>>>(Wc, oi8, oadd);
  k_zfinb<<<kR6, 256, 0, stream>>>(t1rb, mkr, c3rb, coef, t2b);
  // 1x1 conv: batch 48, K=512 real + rank-1 imag epilogue
  gemm<64, 64, false, false>(stream, Wcb, t2b, out, kD, kHW, kD, 2 * kD, kB * kD, kHW,
                             0, 0, (long)kR * kD, kD, 8L * kD * kHW, (long)kD * kHW, 48, oadd);
}